// Round 2
// baseline (425.781 us; speedup 1.0000x reference)
//
#include <hip/hip_runtime.h>

typedef unsigned short u16;
typedef unsigned int   u32;
typedef __attribute__((ext_vector_type(8))) short bf16x8;
typedef __attribute__((ext_vector_type(4))) short s16x4;
typedef __attribute__((ext_vector_type(4))) float f32x4;

#define MFMA16(a,b,c) __builtin_amdgcn_mfma_f32_16x16x32_bf16((a),(b),(c),0,0,0)

__device__ __forceinline__ float bf2f(u16 u){ return __uint_as_float(((u32)u)<<16); }
__device__ __forceinline__ u16 f2bf(float f){
  u32 u = __float_as_uint(f);
  return (u16)((u + 0x7fffu + ((u>>16)&1u)) >> 16);
}
// order-preserving float->uint encoding for atomicMax
__device__ __forceinline__ u32 encf(float f){ u32 u=__float_as_uint(f); return (u&0x80000000u)? ~u : (u|0x80000000u); }
__device__ __forceinline__ float decf(u32 u){ return (u&0x80000000u)? __uint_as_float(u&0x7fffffffu) : __uint_as_float(~u); }

// stage ROWS x 64 bf16 from global (srcStride elems) into LDS padded to 72/row
template<int ROWS>
__device__ __forceinline__ void stage64(u16* dst, const u16* src, int srcStride, int tid){
  #pragma unroll
  for (int u=tid; u<ROWS*8; u+=256){
    int r=u>>3, c=(u&7)<<3;
    *(int4*)&dst[r*72+c] = *(const int4*)&src[(size_t)r*srcStride + c];
  }
}
// same but fp32 source, converted to bf16
template<int ROWS>
__device__ __forceinline__ void stage64f(u16* dst, const float* src, int srcStride, int tid){
  #pragma unroll
  for (int u=tid; u<ROWS*8; u+=256){
    int r=u>>3, c=(u&7)<<3;
    float4 a = *(const float4*)&src[(size_t)r*srcStride + c];
    float4 b = *(const float4*)&src[(size_t)r*srcStride + c + 4];
    u16 tmp[8] = {f2bf(a.x),f2bf(a.y),f2bf(a.z),f2bf(a.w),
                  f2bf(b.x),f2bf(b.y),f2bf(b.z),f2bf(b.w)};
    *(int4*)&dst[r*72+c] = *(const int4*)tmp;
  }
}

// ---------------- init: zero accumulators, build projS = dn*proj (bf16) ----------------
__global__ void k_init(float* ctx, float* kcs, u32* kmaxEnc, u16* projS, const float* __restrict__ proj){
  int i = blockIdx.x*blockDim.x + threadIdx.x;
  int st = gridDim.x*blockDim.x;
  for (int j=i; j<32*512*64; j+=st) ctx[j]=0.f;
  for (int j=i; j<32*512;    j+=st) kcs[j]=0.f;
  for (int j=i; j<32;        j+=st) kmaxEnc[j]=0u;
  const float dn = 0.35355339059327373f; // 64^-0.25
  for (int j=i; j<512*64;    j+=st) projS[j] = f2bf(dn*proj[j]);
}

// ---------------- fp32 512x512 -> bf16 transpose (W -> W^T) ----------------
__global__ __launch_bounds__(256) void k_trw(const float* __restrict__ src, u16* __restrict__ dst){
  __shared__ u16 t[32][34];
  int c0=blockIdx.x*32, r0=blockIdx.y*32;
  int tid=threadIdx.x;
  for (int u=tid; u<1024; u+=256){ int r=u>>5, c=u&31; t[r][c]=f2bf(src[(size_t)(r0+r)*512 + c0+c]); }
  __syncthreads();
  for (int u=tid; u<1024; u+=256){ int c=u>>5, r=u&31; dst[(size_t)(c0+c)*512 + r0+r]=t[r][c]; }
}

// ---------------- v (per b,h 2048x64 slice of [t][512]) -> vT[bh][64][2048] ----------------
__global__ __launch_bounds__(256) void k_trv(const u16* __restrict__ v, u16* __restrict__ vT){
  int bh = blockIdx.z; int b=bh>>3, h=bh&7;
  int d0 = blockIdx.x*32, n0 = blockIdx.y*32;
  __shared__ u16 t[32][34];
  int tid=threadIdx.x;
  const u16* s = v + (size_t)(b*2048)*512 + h*64;
  for (int u=tid; u<1024; u+=256){ int r=u>>5, c=u&31; t[r][c]=s[(size_t)(n0+r)*512 + d0+c]; }
  __syncthreads();
  u16* d = vT + (size_t)bh*64*2048;
  for (int u=tid; u<1024; u+=256){ int c=u>>5, r=u&31; d[(size_t)(d0+c)*2048 + n0+r]=t[r][c]; }
}

// ---------------- ctx f32 [bh][512][64] -> ctxT bf16 [bh][64][512] ----------------
__global__ __launch_bounds__(256) void k_trctx(const float* __restrict__ ctx, u16* __restrict__ ctxT){
  int bh = blockIdx.z;
  int m0 = blockIdx.x*32, d0 = blockIdx.y*32;
  __shared__ float t[32][33];
  int tid=threadIdx.x;
  const float* s = ctx + (size_t)bh*512*64;
  for (int u=tid; u<1024; u+=256){ int r=u>>5, c=u&31; t[r][c]=s[(size_t)(m0+r)*64 + d0+c]; }
  __syncthreads();
  u16* d = ctxT + (size_t)bh*64*512;
  for (int u=tid; u<1024; u+=256){ int c=u>>5, r=u&31; d[(size_t)(d0+c)*512 + m0+r]=f2bf(t[r][c]); }
}

// ---------------- generic GEMM: O[8192x512] = A[8192x512] @ BT^T + bias ----------------
// AF32: A operand is fp32 (converted during staging). OF32: output fp32 (else bf16).
template<bool AF32, bool OF32>
__global__ __launch_bounds__(256) void k_gemm(const void* __restrict__ Av,
    const u16* BT0, const u16* BT1, const u16* BT2,
    const float* b0, const float* b1, const float* b2,
    void* O0, void* O1, void* O2)
{
  int z = blockIdx.z;
  const u16* BT    = z==0?BT0:(z==1?BT1:BT2);
  const float* bias= z==0?b0 :(z==1?b1 :b2 );
  void* Ov         = z==0?O0 :(z==1?O1 :O2 );
  int bm = blockIdx.x*128, bn = blockIdx.y*64;
  __shared__ u16 sA[128*72];
  __shared__ u16 sB[64*72];
  int tid=threadIdx.x, w=tid>>6, lane=tid&63;
  f32x4 acc[8] = {};
  for (int kk=0; kk<512; kk+=64){
    __syncthreads();
    if constexpr (AF32) stage64f<128>(sA, (const float*)Av + (size_t)bm*512 + kk, 512, tid);
    else                stage64 <128>(sA, (const u16*)  Av + (size_t)bm*512 + kk, 512, tid);
    stage64<64>(sB, BT + (size_t)bn*512 + kk, 512, tid);
    __syncthreads();
    int fr = lane&15, kb=(lane>>4)*8;
    #pragma unroll
    for (int rt=0; rt<2; ++rt){
      int ar = (w*2+rt)*16 + fr;
      #pragma unroll
      for (int ct=0; ct<4; ++ct){
        int br = ct*16 + fr;
        #pragma unroll
        for (int kc=0; kc<2; ++kc){
          bf16x8 av = *(const bf16x8*)&sA[ar*72 + kc*32 + kb];
          bf16x8 bv = *(const bf16x8*)&sB[br*72 + kc*32 + kb];
          acc[rt*4+ct] = MFMA16(av,bv,acc[rt*4+ct]);
        }
      }
    }
  }
  int colg = lane&15, rowg=(lane>>4)*4;
  #pragma unroll
  for (int rt=0; rt<2; ++rt){
    #pragma unroll
    for (int ct=0; ct<4; ++ct){
      int col = bn + ct*16 + colg;
      float bv = bias[col];
      #pragma unroll
      for (int j=0;j<4;++j){
        int row = bm + (w*2+rt)*16 + rowg + j;
        if constexpr (OF32) ((float*)Ov)[(size_t)row*512 + col] = acc[rt*4+ct][j] + bv;
        else                ((u16*) Ov)[(size_t)row*512 + col] = f2bf(acc[rt*4+ct][j] + bv);
      }
    }
  }
}

// ---------------- pass 1 over keys: global max of dd per (b,h) ----------------
__global__ __launch_bounds__(256) void k_kmax(const u16* __restrict__ kB, const u16* __restrict__ projS,
                                              u32* __restrict__ kmaxEnc)
{
  int chunk=blockIdx.x, h=blockIdx.y, b=blockIdx.z;
  int bh=b*8+h;
  int t0 = b*2048 + chunk*128;
  __shared__ u16 sK[128*72];
  __shared__ u16 sP[64*72];
  __shared__ float red[4];
  int tid=threadIdx.x, w=tid>>6, lane=tid&63;
  stage64<128>(sK, kB + (size_t)t0*512 + h*64, 512, tid);
  float lm = -3.0e38f;
  int fr=lane&15, kb=(lane>>4)*8;
  for (int mc=0;mc<8;++mc){
    __syncthreads();
    stage64<64>(sP, projS + mc*64*64, 64, tid);
    __syncthreads();
    #pragma unroll
    for (int rt=0;rt<2;++rt){
      int ar=(w*2+rt)*16+fr;
      #pragma unroll
      for (int mt=0;mt<4;++mt){
        f32x4 acc={0.f,0.f,0.f,0.f};
        bf16x8 a0=*(const bf16x8*)&sK[ar*72+kb];
        bf16x8 b0=*(const bf16x8*)&sP[(mt*16+fr)*72+kb];
        acc=MFMA16(a0,b0,acc);
        bf16x8 a1=*(const bf16x8*)&sK[ar*72+32+kb];
        bf16x8 b1=*(const bf16x8*)&sP[(mt*16+fr)*72+32+kb];
        acc=MFMA16(a1,b1,acc);
        lm = fmaxf(lm, fmaxf(fmaxf(acc[0],acc[1]), fmaxf(acc[2],acc[3])));
      }
    }
  }
  #pragma unroll
  for (int m=1;m<64;m<<=1) lm = fmaxf(lm, __shfl_xor(lm,m,64));
  if (lane==0) red[w]=lm;
  __syncthreads();
  if (tid==0){
    float m4 = fmaxf(fmaxf(red[0],red[1]), fmaxf(red[2],red[3]));
    atomicMax(&kmaxEnc[bh], encf(m4));
  }
}

// ---------------- pass 2 over keys: kp -> fb (transposed [h][m][n]), kcs atomics ----------------
__global__ __launch_bounds__(256) void k_kp(const u16* __restrict__ kB, const u16* __restrict__ projS,
    const u32* __restrict__ kmaxEnc, u16* __restrict__ fb, float* __restrict__ kcs, int b)
{
  int chunk=blockIdx.x, h=blockIdx.y;
  int bh=b*8+h;
  int t0 = b*2048 + chunk*128, nloc = chunk*128;
  __shared__ u16 sKd[128*72];
  __shared__ u16 sP[64*72];
  __shared__ u16 sT[64*136];
  __shared__ float diag[128];
  int tid=threadIdx.x, w=tid>>6, lane=tid&63;
  stage64<128>(sKd, kB + (size_t)t0*512 + h*64, 512, tid);
  __syncthreads();
  if (tid<128){
    float s=0.f;
    #pragma unroll
    for (int c=0;c<64;c+=8){
      bf16x8 v=*(const bf16x8*)&sKd[tid*72+c];
      #pragma unroll
      for (int j=0;j<8;++j){ float f=bf2f((u16)v[j]); s+=f*f; }
    }
    diag[tid]=0.0625f*s; // 0.5*dn^2
  }
  float mk = decf(kmaxEnc[bh]);
  const float ratio=0.044194173824159216f; // 512^-0.5
  int fr=lane&15, kb=(lane>>4)*8;
  for (int mc=0;mc<8;++mc){
    __syncthreads();
    stage64<64>(sP, projS + mc*64*64, 64, tid);
    __syncthreads();
    #pragma unroll
    for (int rt=0;rt<2;++rt){
      int rbase=(w*2+rt)*16;
      int ar = rbase + fr;
      #pragma unroll
      for (int mt=0;mt<4;++mt){
        f32x4 acc={0.f,0.f,0.f,0.f};
        bf16x8 a0=*(const bf16x8*)&sKd[ar*72+kb];
        bf16x8 b0=*(const bf16x8*)&sP[(mt*16+fr)*72+kb];
        acc=MFMA16(a0,b0,acc);
        bf16x8 a1=*(const bf16x8*)&sKd[ar*72+32+kb];
        bf16x8 b1=*(const bf16x8*)&sP[(mt*16+fr)*72+32+kb];
        acc=MFMA16(a1,b1,acc);
        int ml = mt*16 + fr;
        int nl = rbase + (lane>>4)*4;
        s16x4 pk;
        #pragma unroll
        for (int j=0;j<4;++j){
          float vk = ratio*(__expf(acc[j] - diag[nl+j] - mk) + 1e-4f);
          pk[j] = (short)f2bf(vk);
        }
        *(s16x4*)&sT[ml*136 + nl] = pk;
      }
    }
    __syncthreads();
    for (int u=tid; u<1024; u+=256){
      int r=u>>4, c=(u&15)<<3;
      *(int4*)&fb[((size_t)h*512 + mc*64 + r)*2048 + nloc + c] = *(const int4*)&sT[r*136 + c];
    }
    if (tid<64){
      float s=0.f;
      for (int n=0;n<128;++n) s += bf2f(sT[tid*136+n]);
      atomicAdd(&kcs[(size_t)bh*512 + mc*64 + tid], s);
    }
  }
}

// ---------------- context[bh][m][d] += kpT @ vT  (split-K over n, atomics) ----------------
__global__ __launch_bounds__(256) void k_ctx(const u16* __restrict__ fb, const u16* __restrict__ vT,
    float* __restrict__ ctx, int b)
{
  int nsp=blockIdx.x, mt4=blockIdx.y, h=blockIdx.z;
  int bh=b*8+h;
  int m0 = mt4*128, n0 = nsp*256;
  __shared__ u16 sA[128*72];
  __shared__ u16 sB[64*72];
  int tid=threadIdx.x, w=tid>>6, lane=tid&63;
  f32x4 acc[8]={};
  for (int kc=0;kc<4;++kc){
    __syncthreads();
    stage64<128>(sA, fb + ((size_t)h*512 + m0)*2048 + n0 + kc*64, 2048, tid);
    stage64<64> (sB, vT + ((size_t)bh*64)*2048 + n0 + kc*64, 2048, tid);
    __syncthreads();
    int fr=lane&15, kb=(lane>>4)*8;
    #pragma unroll
    for (int rt=0;rt<2;++rt){
      int ar=(w*2+rt)*16+fr;
      #pragma unroll
      for (int ct=0;ct<4;++ct){
        int br=ct*16+fr;
        #pragma unroll
        for (int k2=0;k2<2;++k2){
          bf16x8 av=*(const bf16x8*)&sA[ar*72 + k2*32 + kb];
          bf16x8 bv=*(const bf16x8*)&sB[br*72 + k2*32 + kb];
          acc[rt*4+ct]=MFMA16(av,bv,acc[rt*4+ct]);
        }
      }
    }
  }
  int colg=lane&15, rowg=(lane>>4)*4;
  #pragma unroll
  for (int rt=0;rt<2;++rt){
    #pragma unroll
    for (int ct=0;ct<4;++ct){
      #pragma unroll
      for (int j=0;j<4;++j){
        int m = m0 + (w*2+rt)*16 + rowg + j;
        int d = ct*16 + colg;
        atomicAdd(&ctx[((size_t)bh*512 + m)*64 + d], acc[rt*4+ct][j]);
      }
    }
  }
}

// ---------------- q features: qp (bf16) + denominators ----------------
__global__ __launch_bounds__(256) void k_qp(const u16* __restrict__ qB, const u16* __restrict__ projS,
    const float* __restrict__ kcs, u16* __restrict__ qp, float* __restrict__ denom, int b)
{
  int chunk=blockIdx.x, h=blockIdx.y;
  int bh=b*8+h;
  int t0 = b*2048 + chunk*64, nloc = chunk*64;
  __shared__ u16 sQ[64*72];
  __shared__ u16 sP[64*72];
  __shared__ float diag[64];
  __shared__ float sK[512];
  int tid=threadIdx.x, w=tid>>6, lane=tid&63;
  stage64<64>(sQ, qB + (size_t)t0*512 + h*64, 512, tid);
  for (int u=tid; u<512; u+=256) sK[u] = kcs[(size_t)bh*512 + u];
  __syncthreads();
  if (tid<64){
    float s=0.f;
    #pragma unroll
    for (int c=0;c<64;c+=8){
      bf16x8 v=*(const bf16x8*)&sQ[tid*72+c];
      #pragma unroll
      for (int j=0;j<8;++j){ float f=bf2f((u16)v[j]); s+=f*f; }
    }
    diag[tid]=0.0625f*s;
  }
  f32x4 acc[32]={};
  int fr=lane&15, kb=(lane>>4)*8;
  int ar = w*16 + fr;
  #pragma unroll
  for (int mc=0;mc<8;++mc){
    __syncthreads();
    stage64<64>(sP, projS + mc*64*64, 64, tid);
    __syncthreads();
    #pragma unroll
    for (int mt=0;mt<4;++mt){
      bf16x8 a0=*(const bf16x8*)&sQ[ar*72+kb];
      bf16x8 b0=*(const bf16x8*)&sP[(mt*16+fr)*72+kb];
      acc[mc*4+mt]=MFMA16(a0,b0,acc[mc*4+mt]);
      bf16x8 a1=*(const bf16x8*)&sQ[ar*72+32+kb];
      bf16x8 b1=*(const bf16x8*)&sP[(mt*16+fr)*72+32+kb];
      acc[mc*4+mt]=MFMA16(a1,b1,acc[mc*4+mt]);
    }
  }
  float mx[4];
  #pragma unroll
  for (int j=0;j<4;++j){
    float m=-3.0e38f;
    #pragma unroll
    for (int t=0;t<32;++t) m=fmaxf(m, acc[t][j]);
    #pragma unroll
    for (int s=1;s<16;s<<=1) m=fmaxf(m, __shfl_xor(m,s,64));
    mx[j]=m;
  }
  const float ratio=0.044194173824159216f;
  int rowg=(lane>>4)*4;
  float dp[4]={0.f,0.f,0.f,0.f};
  #pragma unroll
  for (int mc=0;mc<8;++mc){
    #pragma unroll
    for (int mt=0;mt<4;++mt){
      int t=mc*4+mt;
      int m = mc*64 + mt*16 + fr;
      float kcv = sK[m];
      #pragma unroll
      for (int j=0;j<4;++j){
        int rl = w*16 + rowg + j;
        float vq = ratio*(__expf(acc[t][j] - diag[rl] - mx[j]) + 1e-4f);
        u16 us = f2bf(vq);
        qp[((size_t)h*2048 + nloc + rl)*512 + m] = us;
        dp[j] += bf2f(us)*kcv;
      }
    }
  }
  #pragma unroll
  for (int j=0;j<4;++j){
    #pragma unroll
    for (int s=1;s<16;s<<=1) dp[j] += __shfl_xor(dp[j],s,64);
  }
  if (fr==0){
    #pragma unroll
    for (int j=0;j<4;++j) denom[(size_t)bh*2048 + nloc + w*16 + rowg + j] = dp[j];
  }
}

// ---------------- out head tile = (qp @ ctxT^T) * 1/denom -> outc ----------------
__global__ __launch_bounds__(256) void k_out(const u16* __restrict__ qp, const u16* __restrict__ ctxT,
    const float* __restrict__ denom, u16* __restrict__ outc, int b)
{
  int chunk=blockIdx.x, h=blockIdx.y;
  int bh=b*8+h;
  int nl0 = chunk*128;
  __shared__ u16 sA[128*72];
  __shared__ u16 sB[64*72];
  int tid=threadIdx.x, w=tid>>6, lane=tid&63;
  f32x4 acc[8]={};
  for (int mc=0;mc<8;++mc){
    __syncthreads();
    stage64<128>(sA, qp   + ((size_t)h*2048 + nl0)*512 + mc*64, 512, tid);
    stage64<64> (sB, ctxT + ((size_t)bh*64)*512 + mc*64, 512, tid);
    __syncthreads();
    int fr=lane&15, kb=(lane>>4)*8;
    #pragma unroll
    for (int rt=0;rt<2;++rt){
      int ar=(w*2+rt)*16+fr;
      #pragma unroll
      for (int ct=0;ct<4;++ct){
        int br=ct*16+fr;
        #pragma unroll
        for (int k2=0;k2<2;++k2){
          bf16x8 av=*(const bf16x8*)&sA[ar*72 + k2*32 + kb];
          bf16x8 bv=*(const bf16x8*)&sB[br*72 + k2*32 + kb];
          acc[rt*4+ct]=MFMA16(av,bv,acc[rt*4+ct]);
        }
      }
    }
  }
  int colg=lane&15, rowg=(lane>>4)*4;
  #pragma unroll
  for (int rt=0;rt<2;++rt){
    #pragma unroll
    for (int ct=0;ct<4;++ct){
      #pragma unroll
      for (int j=0;j<4;++j){
        int tl = nl0 + (w*2+rt)*16 + rowg + j;
        float di = 1.0f/denom[(size_t)bh*2048 + tl];
        int d = ct*16 + colg;
        outc[((size_t)(b*2048 + tl))*512 + h*64 + d] = f2bf(acc[rt*4+ct][j]*di);
      }
    }
  }
}

extern "C" void kernel_launch(void* const* d_in, const int* in_sizes, int n_in,
                              void* d_out, int out_size, void* d_ws, size_t ws_size,
                              hipStream_t stream)
{
  (void)in_sizes; (void)n_in; (void)out_size; (void)ws_size;
  const float* x    = (const float*)d_in[0];
  const float* bq   = (const float*)d_in[2];
  const float* bk   = (const float*)d_in[4];
  const float* bv   = (const float*)d_in[6];
  const float* bo   = (const float*)d_in[8];
  const float* Wq   = (const float*)d_in[1];
  const float* Wk   = (const float*)d_in[3];
  const float* Wv   = (const float*)d_in[5];
  const float* Wo   = (const float*)d_in[7];
  const float* proj = (const float*)d_in[9];

  char* w = (char*)d_ws;
  size_t off=0;
  auto alloc=[&](size_t bytes)->char*{ char* p=w+off; off=(off+bytes+255)&~(size_t)255; return p; };
  u16*  qB   = (u16*)alloc(8192ull*512*2);
  u16*  kBf  = (u16*)alloc(8192ull*512*2);
  u16*  vB   = (u16*)alloc(8192ull*512*2);
  u16*  vT   = (u16*)alloc(32ull*64*2048*2);
  u16*  WqT  = (u16*)alloc(512ull*512*2);
  u16*  WkT  = (u16*)alloc(512ull*512*2);
  u16*  WvT  = (u16*)alloc(512ull*512*2);
  u16*  WoT  = (u16*)alloc(512ull*512*2);
  u16*  projS= (u16*)alloc(512ull*64*2);
  u16*  fb   = (u16*)alloc(8ull*512*2048*2);   // kp^T per-b, then qp per-b
  float* ctx = (float*)alloc(32ull*512*64*4);
  u16*  ctxT = (u16*)alloc(32ull*64*512*2);
  float* kcs = (float*)alloc(32ull*512*4);
  u32*  kmx  = (u32*)alloc(256);
  float* den = (float*)alloc(32ull*2048*4);
  u16*  outc = kBf;  // kBf dead after k_kp; reuse for head-combined output

  dim3 TB(256);
  k_init<<<dim3(256),TB,0,stream>>>(ctx,kcs,kmx,projS,proj);
  k_trw<<<dim3(16,16),TB,0,stream>>>(Wq,WqT);
  k_trw<<<dim3(16,16),TB,0,stream>>>(Wk,WkT);
  k_trw<<<dim3(16,16),TB,0,stream>>>(Wv,WvT);
  k_trw<<<dim3(16,16),TB,0,stream>>>(Wo,WoT);
  k_gemm<true,false><<<dim3(64,8,3),TB,0,stream>>>(x, WqT,WkT,WvT, bq,bk,bv, qB,kBf,vB);
  k_trv<<<dim3(2,64,32),TB,0,stream>>>(vB, vT);
  k_kmax<<<dim3(16,8,4),TB,0,stream>>>(kBf, projS, kmx);
  for (int b=0;b<4;++b){
    k_kp <<<dim3(16,8),TB,0,stream>>>(kBf, projS, kmx, fb, kcs, b);
    k_ctx<<<dim3(8,4,8),TB,0,stream>>>(fb, vT, ctx, b);
  }
  k_trctx<<<dim3(16,2,32),TB,0,stream>>>(ctx, ctxT);
  for (int b=0;b<4;++b){
    k_qp <<<dim3(32,8),TB,0,stream>>>(qB, projS, kcs, fb, den, b);
    k_out<<<dim3(16,8),TB,0,stream>>>(fb, ctxT, den, outc, b);
  }
  k_gemm<false,true><<<dim3(64,8,1),TB,0,stream>>>(outc, WoT,WoT,WoT, bo,bo,bo,
                                                   d_out,d_out,d_out);
}

// Round 3
// 195.919 us; speedup vs baseline: 2.1733x; 2.1733x over previous
//
#include <hip/hip_runtime.h>

typedef unsigned short u16;
typedef unsigned int   u32;
typedef __attribute__((ext_vector_type(8))) short bf16x8;
typedef __attribute__((ext_vector_type(4))) short s16x4;
typedef __attribute__((ext_vector_type(4))) float f32x4;

#define MFMA16(a,b,c) __builtin_amdgcn_mfma_f32_16x16x32_bf16((a),(b),(c),0,0,0)

__device__ __forceinline__ float bf2f(u16 u){ return __uint_as_float(((u32)u)<<16); }
__device__ __forceinline__ u16 f2bf(float f){
  u32 u = __float_as_uint(f);
  return (u16)((u + 0x7fffu + ((u>>16)&1u)) >> 16);
}
__device__ __forceinline__ u32 encf(float f){ u32 u=__float_as_uint(f); return (u&0x80000000u)? ~u : (u|0x80000000u); }
__device__ __forceinline__ float decf(u32 u){ return (u&0x80000000u)? __uint_as_float(u&0x7fffffffu) : __uint_as_float(~u); }

// async global->LDS, 16B per lane, LDS dest = wave-uniform base + lane*16
__device__ __forceinline__ void async_lds16(u16* lds, const u16* g){
  __builtin_amdgcn_global_load_lds((const __attribute__((address_space(1))) void*)g,
                                   (__attribute__((address_space(3))) void*)lds,
                                   16, 0, 0);
}

// stage ROWS x 64 bf16 from global (srcStride elems) into LDS padded to 72/row
template<int ROWS>
__device__ __forceinline__ void stage64(u16* dst, const u16* src, int srcStride, int tid){
  #pragma unroll
  for (int u=tid; u<ROWS*8; u+=256){
    int r=u>>3, c=(u&7)<<3;
    *(int4*)&dst[r*72+c] = *(const int4*)&src[(size_t)r*srcStride + c];
  }
}

// ---------------- init: zero accumulators, projS = dn*proj (bf16), x -> bf16 ----------------
__global__ void k_init(float* ctx, float* kcs, u32* kmaxEnc, u16* projS,
                       const float* __restrict__ proj, const float* __restrict__ x, u16* __restrict__ xb){
  int i = blockIdx.x*blockDim.x + threadIdx.x;
  int st = gridDim.x*blockDim.x;
  for (int j=i; j<32*512*64; j+=st) ctx[j]=0.f;
  for (int j=i; j<32*512;    j+=st) kcs[j]=0.f;
  for (int j=i; j<32;        j+=st) kmaxEnc[j]=0u;
  const float dn = 0.35355339059327373f; // 64^-0.25
  for (int j=i; j<512*64;    j+=st) projS[j] = f2bf(dn*proj[j]);
  // cast x (4M f32) to bf16, 8 at a time
  for (int j=i; j<524288; j+=st){
    float4 a = *(const float4*)&x[(size_t)j*8];
    float4 b = *(const float4*)&x[(size_t)j*8+4];
    u16 tmp[8] = {f2bf(a.x),f2bf(a.y),f2bf(a.z),f2bf(a.w),
                  f2bf(b.x),f2bf(b.y),f2bf(b.z),f2bf(b.w)};
    *(int4*)&xb[(size_t)j*8] = *(const int4*)tmp;
  }
}

// ---------------- fp32 512x512 -> bf16 transpose, batched over 4 weights ----------------
__global__ __launch_bounds__(256) void k_trw(const float* s0, const float* s1, const float* s2, const float* s3,
                                             u16* d0, u16* d1, u16* d2, u16* d3){
  int z = blockIdx.z;
  const float* src = z==0?s0:(z==1?s1:(z==2?s2:s3));
  u16* dst         = z==0?d0:(z==1?d1:(z==2?d2:d3));
  __shared__ u16 t[32][34];
  int c0=blockIdx.x*32, r0=blockIdx.y*32;
  int tid=threadIdx.x;
  for (int u=tid; u<1024; u+=256){ int r=u>>5, c=u&31; t[r][c]=f2bf(src[(size_t)(r0+r)*512 + c0+c]); }
  __syncthreads();
  for (int u=tid; u<1024; u+=256){ int c=u>>5, r=u&31; dst[(size_t)(c0+c)*512 + r0+r]=t[r][c]; }
}

// ---------------- v (per b,h 2048x64 slice of [t][512]) -> vT[bh][64][2048] ----------------
__global__ __launch_bounds__(256) void k_trv(const u16* __restrict__ v, u16* __restrict__ vT){
  int bh = blockIdx.z; int b=bh>>3, h=bh&7;
  int d0 = blockIdx.x*32, n0 = blockIdx.y*32;
  __shared__ u16 t[32][34];
  int tid=threadIdx.x;
  const u16* s = v + (size_t)(b*2048)*512 + h*64;
  for (int u=tid; u<1024; u+=256){ int r=u>>5, c=u&31; t[r][c]=s[(size_t)(n0+r)*512 + d0+c]; }
  __syncthreads();
  u16* d = vT + (size_t)bh*64*2048;
  for (int u=tid; u<1024; u+=256){ int c=u>>5, r=u&31; d[(size_t)(d0+c)*2048 + n0+r]=t[r][c]; }
}

// ---------------- ctx f32 [bh][512][64] -> ctxT bf16 [bh][64][512] ----------------
__global__ __launch_bounds__(256) void k_trctx(const float* __restrict__ ctx, u16* __restrict__ ctxT){
  int bh = blockIdx.z;
  int m0 = blockIdx.x*32, d0 = blockIdx.y*32;
  __shared__ float t[32][33];
  int tid=threadIdx.x;
  const float* s = ctx + (size_t)bh*512*64;
  for (int u=tid; u<1024; u+=256){ int r=u>>5, c=u&31; t[r][c]=s[(size_t)(m0+r)*64 + d0+c]; }
  __syncthreads();
  u16* d = ctxT + (size_t)bh*64*512;
  for (int u=tid; u<1024; u+=256){ int c=u>>5, r=u&31; d[(size_t)(d0+c)*512 + m0+r]=f2bf(t[r][c]); }
}

// ---------------- GEMM m97-style: O[8192x512] = A(bf16) @ BT^T + bias ----------------
template<bool OF32>
__global__ __launch_bounds__(256) void k_gemm2(const u16* __restrict__ A,
    const u16* BT0, const u16* BT1, const u16* BT2,
    const float* b0, const float* b1, const float* b2,
    void* O0, void* O1, void* O2)
{
  int z = blockIdx.z;
  const u16* BT    = z==0?BT0:(z==1?BT1:BT2);
  const float* bias= z==0?b0 :(z==1?b1 :b2 );
  void* Ov         = z==0?O0 :(z==1?O1 :O2 );
  int bm = blockIdx.x*128, bn = blockIdx.y*64;
  __shared__ u16 sA[128*64];   // linear: required by global_load_lds
  __shared__ u16 sB[64*64];
  int tid=threadIdx.x, w=tid>>6, lane=tid&63;
  int lr = lane>>3, lc = (lane&7)*8;
  f32x4 acc[8] = {};
  for (int kk=0; kk<512; kk+=64){
    __syncthreads();
    #pragma unroll
    for (int i=0;i<4;++i){
      int idx = w*4+i;    // 8 rows per call
      async_lds16(&sA[idx*512], A + (size_t)(bm + idx*8 + lr)*512 + kk + lc);
    }
    #pragma unroll
    for (int i=0;i<2;++i){
      int idx = w*2+i;
      async_lds16(&sB[idx*512], BT + (size_t)(bn + idx*8 + lr)*512 + kk + lc);
    }
    __syncthreads();   // compiler drains vmcnt before barrier
    int fr = lane&15, kb=(lane>>4)*8;
    #pragma unroll
    for (int rt=0; rt<2; ++rt){
      int ar = (w*2+rt)*16 + fr;
      #pragma unroll
      for (int ct=0; ct<4; ++ct){
        int br = ct*16 + fr;
        #pragma unroll
        for (int kc=0; kc<2; ++kc){
          bf16x8 av = *(const bf16x8*)&sA[ar*64 + kc*32 + kb];
          bf16x8 bv = *(const bf16x8*)&sB[br*64 + kc*32 + kb];
          acc[rt*4+ct] = MFMA16(av,bv,acc[rt*4+ct]);
        }
      }
    }
  }
  int colg = lane&15, rowg=(lane>>4)*4;
  #pragma unroll
  for (int rt=0; rt<2; ++rt){
    #pragma unroll
    for (int ct=0; ct<4; ++ct){
      int col = bn + ct*16 + colg;
      float bv = bias[col];
      #pragma unroll
      for (int j=0;j<4;++j){
        int row = bm + (w*2+rt)*16 + rowg + j;
        if constexpr (OF32) ((float*)Ov)[(size_t)row*512 + col] = acc[rt*4+ct][j] + bv;
        else                ((u16*) Ov)[(size_t)row*512 + col] = f2bf(acc[rt*4+ct][j] + bv);
      }
    }
  }
}

// ---------------- pass 1 over keys: global max of dd per (b,h) ----------------
__global__ __launch_bounds__(256) void k_kmax(const u16* __restrict__ kB, const u16* __restrict__ projS,
                                              u32* __restrict__ kmaxEnc)
{
  int chunk=blockIdx.x, h=blockIdx.y, b=blockIdx.z;
  int bh=b*8+h;
  int t0 = b*2048 + chunk*128;
  __shared__ u16 sK[128*72];
  __shared__ u16 sP[64*72];
  __shared__ float red[4];
  int tid=threadIdx.x, w=tid>>6, lane=tid&63;
  stage64<128>(sK, kB + (size_t)t0*512 + h*64, 512, tid);
  float lm = -3.0e38f;
  int fr=lane&15, kb=(lane>>4)*8;
  for (int mc=0;mc<8;++mc){
    __syncthreads();
    stage64<64>(sP, projS + mc*64*64, 64, tid);
    __syncthreads();
    #pragma unroll
    for (int rt=0;rt<2;++rt){
      int ar=(w*2+rt)*16+fr;
      #pragma unroll
      for (int mt=0;mt<4;++mt){
        f32x4 acc={0.f,0.f,0.f,0.f};
        bf16x8 a0=*(const bf16x8*)&sK[ar*72+kb];
        bf16x8 b0=*(const bf16x8*)&sP[(mt*16+fr)*72+kb];
        acc=MFMA16(a0,b0,acc);
        bf16x8 a1=*(const bf16x8*)&sK[ar*72+32+kb];
        bf16x8 b1=*(const bf16x8*)&sP[(mt*16+fr)*72+32+kb];
        acc=MFMA16(a1,b1,acc);
        lm = fmaxf(lm, fmaxf(fmaxf(acc[0],acc[1]), fmaxf(acc[2],acc[3])));
      }
    }
  }
  #pragma unroll
  for (int m=1;m<64;m<<=1) lm = fmaxf(lm, __shfl_xor(lm,m,64));
  if (lane==0) red[w]=lm;
  __syncthreads();
  if (tid==0){
    float m4 = fmaxf(fmaxf(red[0],red[1]), fmaxf(red[2],red[3]));
    atomicMax(&kmaxEnc[bh], encf(m4));
  }
}

// ---------------- fused: kp features + ctx partial GEMM + kcs (per 128-n chunk) ----------------
__global__ __launch_bounds__(256) void k_kpctx(const u16* __restrict__ kB, const u16* __restrict__ projS,
    const u16* __restrict__ vT, const u32* __restrict__ kmaxEnc,
    float* __restrict__ ctx, float* __restrict__ kcs)
{
  int chunk=blockIdx.x, h=blockIdx.y, b=blockIdx.z;
  int bh=b*8+h;
  int t0 = b*2048 + chunk*128;
  __shared__ u16 sKd[128*72];
  __shared__ u16 sV [64*136];   // [d=64][n=128]
  __shared__ u16 sP [64*72];
  __shared__ u16 sT [64*136];   // kp tile [m=64][n=128]
  __shared__ float diag[128];
  int tid=threadIdx.x, w=tid>>6, lane=tid&63;
  stage64<128>(sKd, kB + (size_t)t0*512 + h*64, 512, tid);
  {
    const u16* src = vT + (size_t)bh*64*2048 + chunk*128;
    for (int u=tid; u<1024; u+=256){
      int r=u>>4, c=(u&15)<<3;
      *(int4*)&sV[r*136+c] = *(const int4*)&src[(size_t)r*2048 + c];
    }
  }
  __syncthreads();
  if (tid<128){
    float s=0.f;
    #pragma unroll
    for (int c=0;c<64;c+=8){
      bf16x8 v=*(const bf16x8*)&sKd[tid*72+c];
      #pragma unroll
      for (int j=0;j<8;++j){ float f=bf2f((u16)v[j]); s+=f*f; }
    }
    diag[tid]=0.0625f*s; // 0.5*dn^2
  }
  float mk = decf(kmaxEnc[bh]);
  const float ratio=0.044194173824159216f; // 512^-0.5
  int fr=lane&15, kb=(lane>>4)*8;
  for (int mc=0;mc<8;++mc){
    __syncthreads();
    stage64<64>(sP, projS + mc*64*64, 64, tid);
    __syncthreads();
    // features: dd[n=128][m=64] -> exp -> sT[m][n]
    #pragma unroll
    for (int rt=0;rt<2;++rt){
      int rbase=(w*2+rt)*16;
      int ar = rbase + fr;
      #pragma unroll
      for (int mt=0;mt<4;++mt){
        f32x4 acc={0.f,0.f,0.f,0.f};
        bf16x8 a0=*(const bf16x8*)&sKd[ar*72+kb];
        bf16x8 b0=*(const bf16x8*)&sP[(mt*16+fr)*72+kb];
        acc=MFMA16(a0,b0,acc);
        bf16x8 a1=*(const bf16x8*)&sKd[ar*72+32+kb];
        bf16x8 b1=*(const bf16x8*)&sP[(mt*16+fr)*72+32+kb];
        acc=MFMA16(a1,b1,acc);
        int ml = mt*16 + fr;
        int nl = rbase + (lane>>4)*4;
        s16x4 pk;
        #pragma unroll
        for (int j=0;j<4;++j){
          float vk = ratio*(__expf(acc[j] - diag[nl+j] - mk) + 1e-4f);
          pk[j] = (short)f2bf(vk);
        }
        *(s16x4*)&sT[ml*136 + nl] = pk;
      }
    }
    __syncthreads();
    // ctx partial: [64 m][64 d] += sT[64 m][128 n] @ sV[64 d][128 n]^T
    f32x4 accc[4]={};
    int am = w*16 + fr;
    #pragma unroll
    for (int ct=0;ct<4;++ct){
      #pragma unroll
      for (int ks=0;ks<4;++ks){
        bf16x8 av=*(const bf16x8*)&sT[am*136 + ks*32 + kb];
        bf16x8 bv=*(const bf16x8*)&sV[(ct*16+fr)*136 + ks*32 + kb];
        accc[ct]=MFMA16(av,bv,accc[ct]);
      }
    }
    // kcs partial: sum sT over n per m
    {
      int m = tid>>2, q = tid&3;
      float s=0.f;
      #pragma unroll
      for (int n=0;n<32;++n) s += bf2f(sT[m*136 + q*32 + n]);
      s += __shfl_xor(s,1,64); s += __shfl_xor(s,2,64);
      if (q==0) atomicAdd(&kcs[(size_t)bh*512 + mc*64 + m], s);
    }
    int rowg=(lane>>4)*4;
    #pragma unroll
    for (int ct=0;ct<4;++ct){
      #pragma unroll
      for (int j=0;j<4;++j){
        atomicAdd(&ctx[((size_t)bh*512 + mc*64 + w*16 + rowg + j)*64 + ct*16 + fr], accc[ct][j]);
      }
    }
  }
}

// ---------------- fused: q features + PV GEMM + denom scale -> outc ----------------
__global__ __launch_bounds__(256) void k_qpout(const u16* __restrict__ qB, const u16* __restrict__ projS,
    const float* __restrict__ kcs, const u16* __restrict__ ctxT,
    u16* __restrict__ outc)
{
  int chunk=blockIdx.x, h=blockIdx.y, b=blockIdx.z;
  int bh=b*8+h;
  int t0 = b*2048 + chunk*64;
  __shared__ u16 pool[2*64*264];   // feature phase: sQ(64*72)+sP(64*72); PV phase: qpL(64*264)+sCt(64*264)
  u16* sQ  = pool;
  u16* sP  = pool + 64*72;
  u16* qpL = pool;
  u16* sCt = pool + 64*264;
  __shared__ float sK[512];
  __shared__ float diag[64];
  int tid=threadIdx.x, w=tid>>6, lane=tid&63;
  stage64<64>(sQ, qB + (size_t)t0*512 + h*64, 512, tid);
  for (int u=tid; u<512; u+=256) sK[u] = kcs[(size_t)bh*512 + u];
  __syncthreads();
  if (tid<64){
    float s=0.f;
    #pragma unroll
    for (int c=0;c<64;c+=8){
      bf16x8 v=*(const bf16x8*)&sQ[tid*72+c];
      #pragma unroll
      for (int j=0;j<8;++j){ float f=bf2f((u16)v[j]); s+=f*f; }
    }
    diag[tid]=0.0625f*s;
  }
  f32x4 acc[32]={};
  int fr=lane&15, kb=(lane>>4)*8;
  int ar = w*16 + fr;
  #pragma unroll
  for (int mc=0;mc<8;++mc){
    __syncthreads();
    stage64<64>(sP, projS + mc*64*64, 64, tid);
    __syncthreads();
    #pragma unroll
    for (int mt=0;mt<4;++mt){
      bf16x8 a0=*(const bf16x8*)&sQ[ar*72+kb];
      bf16x8 b0=*(const bf16x8*)&sP[(mt*16+fr)*72+kb];
      acc[mc*4+mt]=MFMA16(a0,b0,acc[mc*4+mt]);
      bf16x8 a1=*(const bf16x8*)&sQ[ar*72+32+kb];
      bf16x8 b1=*(const bf16x8*)&sP[(mt*16+fr)*72+32+kb];
      acc[mc*4+mt]=MFMA16(a1,b1,acc[mc*4+mt]);
    }
  }
  float mx[4];
  #pragma unroll
  for (int j=0;j<4;++j){
    float m=-3.0e38f;
    #pragma unroll
    for (int t=0;t<32;++t) m=fmaxf(m, acc[t][j]);
    #pragma unroll
    for (int s=1;s<16;s<<=1) m=fmaxf(m, __shfl_xor(m,s,64));
    mx[j]=m;
  }
  const float ratio=0.044194173824159216f;
  int rowg=(lane>>4)*4;
  float dp[4]={0.f,0.f,0.f,0.f};
  f32x4 acc2[4]={};
  #pragma unroll
  for (int half=0; half<2; ++half){
    __syncthreads();   // protect pool reuse / previous-half reads
    #pragma unroll
    for (int mc4=0; mc4<4; ++mc4){
      #pragma unroll
      for (int mt=0; mt<4; ++mt){
        int t = half*16 + mc4*4 + mt;
        int mloc = mc4*64 + mt*16 + fr;
        float kcv = sK[half*256 + mloc];
        #pragma unroll
        for (int j=0;j<4;++j){
          int rl = w*16 + rowg + j;
          float vq = ratio*(__expf(acc[t][j] - diag[rl] - mx[j]) + 1e-4f);
          u16 us = f2bf(vq);
          qpL[rl*264 + mloc] = us;
          dp[j] += bf2f(us)*kcv;
        }
      }
    }
    {
      const u16* src = ctxT + (size_t)bh*64*512 + half*256;
      for (int u=tid; u<2048; u+=256){
        int r=u>>5, c=(u&31)<<3;
        *(int4*)&sCt[r*264+c] = *(const int4*)&src[(size_t)r*512 + c];
      }
    }
    __syncthreads();
    #pragma unroll
    for (int ct=0; ct<4; ++ct){
      #pragma unroll
      for (int ks=0; ks<8; ++ks){
        bf16x8 av=*(const bf16x8*)&qpL[(w*16+fr)*264 + ks*32 + kb];
        bf16x8 bv=*(const bf16x8*)&sCt[(ct*16+fr)*264 + ks*32 + kb];
        acc2[ct]=MFMA16(av,bv,acc2[ct]);
      }
    }
  }
  #pragma unroll
  for (int j=0;j<4;++j){
    #pragma unroll
    for (int s=1;s<16;s<<=1) dp[j] += __shfl_xor(dp[j],s,64);
  }
  #pragma unroll
  for (int ct=0; ct<4; ++ct){
    #pragma unroll
    for (int j=0;j<4;++j){
      int row = b*2048 + chunk*64 + w*16 + rowg + j;
      outc[(size_t)row*512 + h*64 + ct*16 + fr] = f2bf(acc2[ct][j] / dp[j]);
    }
  }
}

extern "C" void kernel_launch(void* const* d_in, const int* in_sizes, int n_in,
                              void* d_out, int out_size, void* d_ws, size_t ws_size,
                              hipStream_t stream)
{
  (void)in_sizes; (void)n_in; (void)out_size; (void)ws_size;
  const float* x    = (const float*)d_in[0];
  const float* Wq   = (const float*)d_in[1];
  const float* bq   = (const float*)d_in[2];
  const float* Wk   = (const float*)d_in[3];
  const float* bk   = (const float*)d_in[4];
  const float* Wv   = (const float*)d_in[5];
  const float* bv   = (const float*)d_in[6];
  const float* Wo   = (const float*)d_in[7];
  const float* bo   = (const float*)d_in[8];
  const float* proj = (const float*)d_in[9];

  char* w = (char*)d_ws;
  size_t off=0;
  auto alloc=[&](size_t bytes)->char*{ char* p=w+off; off=(off+bytes+255)&~(size_t)255; return p; };
  u16*  xb   = (u16*)alloc(8192ull*512*2);
  u16*  qB   = (u16*)alloc(8192ull*512*2);
  u16*  kBf  = (u16*)alloc(8192ull*512*2);
  u16*  vB   = (u16*)alloc(8192ull*512*2);
  u16*  vT   = (u16*)alloc(32ull*64*2048*2);
  u16*  WqT  = (u16*)alloc(512ull*512*2);
  u16*  WkT  = (u16*)alloc(512ull*512*2);
  u16*  WvT  = (u16*)alloc(512ull*512*2);
  u16*  WoT  = (u16*)alloc(512ull*512*2);
  u16*  projS= (u16*)alloc(512ull*64*2);
  float* ctx = (float*)alloc(32ull*512*64*4);
  u16*  ctxT = (u16*)alloc(32ull*64*512*2);
  float* kcs = (float*)alloc(32ull*512*4);
  u32*  kmx  = (u32*)alloc(256);
  u16*  outc = kBf;  // kBf dead after k_kpctx; reuse

  dim3 TB(256);
  k_init<<<dim3(256),TB,0,stream>>>(ctx,kcs,kmx,projS,proj,x,xb);
  k_trw<<<dim3(16,16,4),TB,0,stream>>>(Wq,Wk,Wv,Wo, WqT,WkT,WvT,WoT);
  k_gemm2<false><<<dim3(64,8,3),TB,0,stream>>>(xb, WqT,WkT,WvT, bq,bk,bv, qB,kBf,vB);
  k_trv<<<dim3(2,64,32),TB,0,stream>>>(vB, vT);
  k_kmax<<<dim3(16,8,4),TB,0,stream>>>(kBf, projS, kmx);
  k_kpctx<<<dim3(16,8,4),TB,0,stream>>>(kBf, projS, vT, kmx, ctx, kcs);
  k_trctx<<<dim3(16,2,32),TB,0,stream>>>(ctx, ctxT);
  k_qpout<<<dim3(32,8,4),TB,0,stream>>>(qB, projS, kcs, ctxT, outc);
  k_gemm2<true><<<dim3(64,8,1),TB,0,stream>>>(outc, WoT,WoT,WoT, bo,bo,bo,
                                              d_out,d_out,d_out);
}

// Round 4
// 175.583 us; speedup vs baseline: 2.4250x; 1.1158x over previous
//
#include <hip/hip_runtime.h>

typedef unsigned short u16;
typedef unsigned int   u32;
typedef __attribute__((ext_vector_type(8))) short bf16x8;
typedef __attribute__((ext_vector_type(4))) short s16x4;
typedef __attribute__((ext_vector_type(4))) float f32x4;

#define MFMA16(a,b,c) __builtin_amdgcn_mfma_f32_16x16x32_bf16((a),(b),(c),0,0,0)

__device__ __forceinline__ float bf2f(u16 u){ return __uint_as_float(((u32)u)<<16); }
__device__ __forceinline__ u16 f2bf(float f){
  u32 u = __float_as_uint(f);
  return (u16)((u + 0x7fffu + ((u>>16)&1u)) >> 16);
}
__device__ __forceinline__ u32 encf(float f){ u32 u=__float_as_uint(f); return (u&0x80000000u)? ~u : (u|0x80000000u); }
__device__ __forceinline__ float decf(u32 u){ return (u&0x80000000u)? __uint_as_float(u&0x7fffffffu) : __uint_as_float(~u); }

// async global->LDS, 16B per lane, LDS dest = wave-uniform base + lane*16
__device__ __forceinline__ void async_lds16(u16* lds, const u16* g){
  __builtin_amdgcn_global_load_lds((const __attribute__((address_space(1))) void*)g,
                                   (__attribute__((address_space(3))) void*)lds,
                                   16, 0, 0);
}

// stage ROWS x 64 bf16 from global (srcStride elems) into LDS padded to 72/row
template<int ROWS>
__device__ __forceinline__ void stage64(u16* dst, const u16* src, int srcStride, int tid){
  #pragma unroll
  for (int u=tid; u<ROWS*8; u+=256){
    int r=u>>3, c=(u&7)<<3;
    *(int4*)&dst[r*72+c] = *(const int4*)&src[(size_t)r*srcStride + c];
  }
}

// ---------------- init: zero accumulators, projS = dn*proj (bf16), x -> bf16 ----------------
__global__ void k_init(float* ctx, float* kcs, u32* kmaxEnc, u16* projS,
                       const float* __restrict__ proj, const float* __restrict__ x, u16* __restrict__ xb){
  int i = blockIdx.x*blockDim.x + threadIdx.x;
  int st = gridDim.x*blockDim.x;
  for (int j=i; j<32*512*64; j+=st) ctx[j]=0.f;
  for (int j=i; j<32*512;    j+=st) kcs[j]=0.f;
  for (int j=i; j<32;        j+=st) kmaxEnc[j]=0u;
  const float dn = 0.35355339059327373f; // 64^-0.25
  for (int j=i; j<512*64;    j+=st) projS[j] = f2bf(dn*proj[j]);
  for (int j=i; j<524288; j+=st){
    float4 a = *(const float4*)&x[(size_t)j*8];
    float4 b = *(const float4*)&x[(size_t)j*8+4];
    u16 tmp[8] = {f2bf(a.x),f2bf(a.y),f2bf(a.z),f2bf(a.w),
                  f2bf(b.x),f2bf(b.y),f2bf(b.z),f2bf(b.w)};
    *(int4*)&xb[(size_t)j*8] = *(const int4*)tmp;
  }
}

// ---------------- fp32 512x512 -> bf16 transpose, batched over 4 weights ----------------
__global__ __launch_bounds__(256) void k_trw(const float* s0, const float* s1, const float* s2, const float* s3,
                                             u16* d0, u16* d1, u16* d2, u16* d3){
  int z = blockIdx.z;
  const float* src = z==0?s0:(z==1?s1:(z==2?s2:s3));
  u16* dst         = z==0?d0:(z==1?d1:(z==2?d2:d3));
  __shared__ u16 t[32][34];
  int c0=blockIdx.x*32, r0=blockIdx.y*32;
  int tid=threadIdx.x;
  for (int u=tid; u<1024; u+=256){ int r=u>>5, c=u&31; t[r][c]=f2bf(src[(size_t)(r0+r)*512 + c0+c]); }
  __syncthreads();
  for (int u=tid; u<1024; u+=256){ int c=u>>5, r=u&31; dst[(size_t)(c0+c)*512 + r0+r]=t[r][c]; }
}

// ---------------- v (per b,h 2048x64 slice of [t][512]) -> vT[bh][64][2048] ----------------
__global__ __launch_bounds__(256) void k_trv(const u16* __restrict__ v, u16* __restrict__ vT){
  int bh = blockIdx.z; int b=bh>>3, h=bh&7;
  int d0 = blockIdx.x*32, n0 = blockIdx.y*32;
  __shared__ u16 t[32][34];
  int tid=threadIdx.x;
  const u16* s = v + (size_t)(b*2048)*512 + h*64;
  for (int u=tid; u<1024; u+=256){ int r=u>>5, c=u&31; t[r][c]=s[(size_t)(n0+r)*512 + d0+c]; }
  __syncthreads();
  u16* d = vT + (size_t)bh*64*2048;
  for (int u=tid; u<1024; u+=256){ int c=u>>5, r=u&31; d[(size_t)(d0+c)*2048 + n0+r]=t[r][c]; }
}

// ---------------- ctx f32 [bh][512][64] -> ctxT bf16 [bh][64][512] ----------------
__global__ __launch_bounds__(256) void k_trctx(const float* __restrict__ ctx, u16* __restrict__ ctxT){
  int bh = blockIdx.z;
  int m0 = blockIdx.x*32, d0 = blockIdx.y*32;
  __shared__ float t[32][33];
  int tid=threadIdx.x;
  const float* s = ctx + (size_t)bh*512*64;
  for (int u=tid; u<1024; u+=256){ int r=u>>5, c=u&31; t[r][c]=s[(size_t)(m0+r)*64 + d0+c]; }
  __syncthreads();
  u16* d = ctxT + (size_t)bh*64*512;
  for (int u=tid; u<1024; u+=256){ int c=u>>5, r=u&31; d[(size_t)(d0+c)*512 + m0+r]=f2bf(t[r][c]); }
}

// ---------------- per-bh sums for the analytic eps term ----------------
__global__ __launch_bounds__(256) void k_sums(const u16* __restrict__ ctxT, const float* __restrict__ kcs,
                                              float* __restrict__ ctxsum, float* __restrict__ kcssum){
  int bh = blockIdx.x;
  int tid = threadIdx.x;
  int d = tid&63, part = tid>>6;
  const u16* src = ctxT + (size_t)bh*64*512 + (size_t)d*512 + part*128;
  float s=0.f;
  for (int m=0;m<128;m+=8){
    bf16x8 v = *(const bf16x8*)&src[m];
    #pragma unroll
    for (int j=0;j<8;++j) s += bf2f((u16)v[j]);
  }
  __shared__ float red[256];
  __shared__ float red2[256];
  red[tid]=s;
  float t=0.f;
  for (int u=tid;u<512;u+=256) t += kcs[(size_t)bh*512+u];
  red2[tid]=t;
  __syncthreads();
  if (part==0) ctxsum[bh*64+d] = red[d]+red[64+d]+red[128+d]+red[192+d];
  if (tid<64){
    float a=red2[tid]+red2[tid+64]+red2[tid+128]+red2[tid+192];
    #pragma unroll
    for (int m2=1;m2<64;m2<<=1) a += __shfl_xor(a,m2,64);
    if (tid==0) kcssum[bh]=a;
  }
}

// ---------------- GEMM m97-style: O[8192x512] = A(bf16) @ BT^T + bias ----------------
template<bool OF32>
__global__ __launch_bounds__(256) void k_gemm2(const u16* __restrict__ A,
    const u16* BT0, const u16* BT1, const u16* BT2,
    const float* b0, const float* b1, const float* b2,
    void* O0, void* O1, void* O2)
{
  int z = blockIdx.z;
  const u16* BT    = z==0?BT0:(z==1?BT1:BT2);
  const float* bias= z==0?b0 :(z==1?b1 :b2 );
  void* Ov         = z==0?O0 :(z==1?O1 :O2 );
  int bm = blockIdx.x*128, bn = blockIdx.y*64;
  __shared__ u16 sA[128*64];
  __shared__ u16 sB[64*64];
  int tid=threadIdx.x, w=tid>>6, lane=tid&63;
  int lr = lane>>3, lc = (lane&7)*8;
  f32x4 acc[8] = {};
  for (int kk=0; kk<512; kk+=64){
    __syncthreads();
    #pragma unroll
    for (int i=0;i<4;++i){
      int idx = w*4+i;
      async_lds16(&sA[idx*512], A + (size_t)(bm + idx*8 + lr)*512 + kk + lc);
    }
    #pragma unroll
    for (int i=0;i<2;++i){
      int idx = w*2+i;
      async_lds16(&sB[idx*512], BT + (size_t)(bn + idx*8 + lr)*512 + kk + lc);
    }
    __syncthreads();
    int fr = lane&15, kb=(lane>>4)*8;
    #pragma unroll
    for (int rt=0; rt<2; ++rt){
      int ar = (w*2+rt)*16 + fr;
      #pragma unroll
      for (int ct=0; ct<4; ++ct){
        int br = ct*16 + fr;
        #pragma unroll
        for (int kc=0; kc<2; ++kc){
          bf16x8 av = *(const bf16x8*)&sA[ar*64 + kc*32 + kb];
          bf16x8 bv = *(const bf16x8*)&sB[br*64 + kc*32 + kb];
          acc[rt*4+ct] = MFMA16(av,bv,acc[rt*4+ct]);
        }
      }
    }
  }
  int colg = lane&15, rowg=(lane>>4)*4;
  #pragma unroll
  for (int rt=0; rt<2; ++rt){
    #pragma unroll
    for (int ct=0; ct<4; ++ct){
      int col = bn + ct*16 + colg;
      float bv = bias[col];
      #pragma unroll
      for (int j=0;j<4;++j){
        int row = bm + (w*2+rt)*16 + rowg + j;
        if constexpr (OF32) ((float*)Ov)[(size_t)row*512 + col] = acc[rt*4+ct][j] + bv;
        else                ((u16*) Ov)[(size_t)row*512 + col] = f2bf(acc[rt*4+ct][j] + bv);
      }
    }
  }
}

// ---------------- pass 1 over keys: global max of dd per (b,h) ----------------
__global__ __launch_bounds__(256) void k_kmax(const u16* __restrict__ kB, const u16* __restrict__ projS,
                                              u32* __restrict__ kmaxEnc)
{
  int chunk=blockIdx.x, h=blockIdx.y, b=blockIdx.z;
  int bh=b*8+h;
  int t0 = b*2048 + chunk*128;
  __shared__ u16 sK[128*72];
  __shared__ u16 sP[64*72];
  __shared__ float red[4];
  int tid=threadIdx.x, w=tid>>6, lane=tid&63;
  stage64<128>(sK, kB + (size_t)t0*512 + h*64, 512, tid);
  float lm = -3.0e38f;
  int fr=lane&15, kb=(lane>>4)*8;
  for (int mc=0;mc<8;++mc){
    __syncthreads();
    stage64<64>(sP, projS + mc*64*64, 64, tid);
    __syncthreads();
    #pragma unroll
    for (int rt=0;rt<2;++rt){
      int ar=(w*2+rt)*16+fr;
      #pragma unroll
      for (int mt=0;mt<4;++mt){
        f32x4 acc={0.f,0.f,0.f,0.f};
        bf16x8 a0=*(const bf16x8*)&sK[ar*72+kb];
        bf16x8 b0=*(const bf16x8*)&sP[(mt*16+fr)*72+kb];
        acc=MFMA16(a0,b0,acc);
        bf16x8 a1=*(const bf16x8*)&sK[ar*72+32+kb];
        bf16x8 b1=*(const bf16x8*)&sP[(mt*16+fr)*72+32+kb];
        acc=MFMA16(a1,b1,acc);
        lm = fmaxf(lm, fmaxf(fmaxf(acc[0],acc[1]), fmaxf(acc[2],acc[3])));
      }
    }
  }
  #pragma unroll
  for (int m=1;m<64;m<<=1) lm = fmaxf(lm, __shfl_xor(lm,m,64));
  if (lane==0) red[w]=lm;
  __syncthreads();
  if (tid==0){
    float m4 = fmaxf(fmaxf(red[0],red[1]), fmaxf(red[2],red[3]));
    atomicMax(&kmaxEnc[bh], encf(m4));
  }
}

// ---------------- fused: kp features + ctx partial GEMM + kcs (per 128-n chunk) ----------------
__global__ __launch_bounds__(256) void k_kpctx(const u16* __restrict__ kB, const u16* __restrict__ projS,
    const u16* __restrict__ vT, const u32* __restrict__ kmaxEnc,
    float* __restrict__ ctx, float* __restrict__ kcs)
{
  int chunk=blockIdx.x, h=blockIdx.y, b=blockIdx.z;
  int bh=b*8+h;
  int t0 = b*2048 + chunk*128;
  __shared__ u16 sKd[128*72];
  __shared__ u16 sV [64*136];
  __shared__ u16 sP [64*72];
  __shared__ u16 sT [64*136];
  __shared__ float diag[128];
  int tid=threadIdx.x, w=tid>>6, lane=tid&63;
  stage64<128>(sKd, kB + (size_t)t0*512 + h*64, 512, tid);
  {
    const u16* src = vT + (size_t)bh*64*2048 + chunk*128;
    for (int u=tid; u<1024; u+=256){
      int r=u>>4, c=(u&15)<<3;
      *(int4*)&sV[r*136+c] = *(const int4*)&src[(size_t)r*2048 + c];
    }
  }
  __syncthreads();
  if (tid<128){
    float s=0.f;
    #pragma unroll
    for (int c=0;c<64;c+=8){
      bf16x8 v=*(const bf16x8*)&sKd[tid*72+c];
      #pragma unroll
      for (int j=0;j<8;++j){ float f=bf2f((u16)v[j]); s+=f*f; }
    }
    diag[tid]=0.0625f*s;
  }
  float mk = decf(kmaxEnc[bh]);
  const float ratio=0.044194173824159216f;
  int fr=lane&15, kb=(lane>>4)*8;
  for (int mc=0;mc<8;++mc){
    __syncthreads();
    stage64<64>(sP, projS + mc*64*64, 64, tid);
    __syncthreads();
    #pragma unroll
    for (int rt=0;rt<2;++rt){
      int rbase=(w*2+rt)*16;
      int ar = rbase + fr;
      #pragma unroll
      for (int mt=0;mt<4;++mt){
        f32x4 acc={0.f,0.f,0.f,0.f};
        bf16x8 a0=*(const bf16x8*)&sKd[ar*72+kb];
        bf16x8 b0=*(const bf16x8*)&sP[(mt*16+fr)*72+kb];
        acc=MFMA16(a0,b0,acc);
        bf16x8 a1=*(const bf16x8*)&sKd[ar*72+32+kb];
        bf16x8 b1=*(const bf16x8*)&sP[(mt*16+fr)*72+32+kb];
        acc=MFMA16(a1,b1,acc);
        int ml = mt*16 + fr;
        int nl = rbase + (lane>>4)*4;
        s16x4 pk;
        #pragma unroll
        for (int j=0;j<4;++j){
          float vk = ratio*(__expf(acc[j] - diag[nl+j] - mk) + 1e-4f);
          pk[j] = (short)f2bf(vk);
        }
        *(s16x4*)&sT[ml*136 + nl] = pk;
      }
    }
    __syncthreads();
    f32x4 accc[4]={};
    int am = w*16 + fr;
    #pragma unroll
    for (int ct=0;ct<4;++ct){
      #pragma unroll
      for (int ks=0;ks<4;++ks){
        bf16x8 av=*(const bf16x8*)&sT[am*136 + ks*32 + kb];
        bf16x8 bv=*(const bf16x8*)&sV[(ct*16+fr)*136 + ks*32 + kb];
        accc[ct]=MFMA16(av,bv,accc[ct]);
      }
    }
    {
      int m = tid>>2, q = tid&3;
      float s=0.f;
      #pragma unroll
      for (int n=0;n<32;++n) s += bf2f(sT[m*136 + q*32 + n]);
      s += __shfl_xor(s,1,64); s += __shfl_xor(s,2,64);
      if (q==0) atomicAdd(&kcs[(size_t)bh*512 + mc*64 + m], s);
    }
    int rowg=(lane>>4)*4;
    #pragma unroll
    for (int ct=0;ct<4;++ct){
      #pragma unroll
      for (int j=0;j<4;++j){
        atomicAdd(&ctx[((size_t)bh*512 + mc*64 + w*16 + rowg + j)*64 + ct*16 + fr], accc[ct][j]);
      }
    }
  }
}

// ---------------- fused flash-style: q features (online max) + PV + exact eps ----------------
__global__ __launch_bounds__(256) void k_qpout2(const u16* __restrict__ qB, const u16* __restrict__ projS,
    const float* __restrict__ kcs, const u16* __restrict__ ctxT,
    const float* __restrict__ ctxsum, const float* __restrict__ kcssum,
    u16* __restrict__ outc)
{
  int chunk=blockIdx.x, h=blockIdx.y, b=blockIdx.z;
  int bh=b*8+h;
  int t0 = b*2048 + chunk*128;
  __shared__ u16 sP[2][64*64];     // proj chunk double-buffered (linear: async dest)
  __shared__ u16 sCt[2][64*64];    // ctxT chunk double-buffered
  __shared__ u16 qpL[128*72];      // qp chunk, padded (VALU-written)
  __shared__ float sK[512];
  __shared__ float diag[128];
  int tid=threadIdx.x, w=tid>>6, lane=tid&63;
  int fr=lane&15, kb=(lane>>4)*8, rowg=(lane>>4)*4;
  // q fragments in registers: rows w*32 + rt*16 + fr, k = kc*32 + kb .. +8
  bf16x8 qf[2][2];
  #pragma unroll
  for (int rt=0;rt<2;++rt)
    #pragma unroll
    for (int kc=0;kc<2;++kc)
      qf[rt][kc] = *(const bf16x8*)&qB[(size_t)(t0 + w*32 + rt*16 + fr)*512 + h*64 + kc*32 + kb];
  // diag from q regs: per-lane partial (16 of 64 k), reduce across lane>>4 groups
  #pragma unroll
  for (int rt=0;rt<2;++rt){
    float s=0.f;
    #pragma unroll
    for (int kc=0;kc<2;++kc)
      #pragma unroll
      for (int j=0;j<8;++j){ float f=bf2f((u16)qf[rt][kc][j]); s+=f*f; }
    s += __shfl_xor(s,16,64); s += __shfl_xor(s,32,64);
    if (lane<16) diag[w*32 + rt*16 + fr] = 0.0625f*s;
  }
  for (int u=tid; u<512; u+=256) sK[u] = kcs[(size_t)bh*512 + u];
  // stage chunk 0
  {
    const u16* gp = projS;
    const u16* gc = ctxT + (size_t)bh*64*512;
    int lr=lane>>3, lc=(lane&7)*8;
    #pragma unroll
    for (int i=0;i<2;++i){
      int idx = w*2+i;
      async_lds16(&sP[0][idx*512], gp + idx*512 + lane*8);
      async_lds16(&sCt[0][idx*512], gc + (size_t)(idx*8+lr)*512 + lc);
    }
  }
  f32x4 acc2[2][4]={};
  float mx[2][4], dp[2][4];
  #pragma unroll
  for (int rt=0;rt<2;++rt)
    #pragma unroll
    for (int j=0;j<4;++j){ mx[rt][j]=-3.0e38f; dp[rt][j]=0.f; }
  __syncthreads();   // drains chunk0 asyncs + diag/sK writes
  for (int mc=0; mc<8; ++mc){
    int cur = mc&1;
    if (mc<7){
      int nxt = cur^1;
      const u16* gp = projS + (mc+1)*64*64;
      const u16* gc = ctxT + (size_t)bh*64*512 + (mc+1)*64;
      int lr=lane>>3, lc=(lane&7)*8;
      #pragma unroll
      for (int i=0;i<2;++i){
        int idx = w*2+i;
        async_lds16(&sP[nxt][idx*512], gp + idx*512 + lane*8);
        async_lds16(&sCt[nxt][idx*512], gc + (size_t)(idx*8+lr)*512 + lc);
      }
    }
    // feature MFMA: dd chunk [128 rows][64 m], A from regs
    f32x4 facc[2][4];
    #pragma unroll
    for (int rt=0;rt<2;++rt){
      #pragma unroll
      for (int mt=0;mt<4;++mt){
        f32x4 a={0.f,0.f,0.f,0.f};
        #pragma unroll
        for (int kc=0;kc<2;++kc){
          bf16x8 bv = *(const bf16x8*)&sP[cur][(mt*16+fr)*64 + kc*32 + kb];
          a = MFMA16(qf[rt][kc], bv, a);
        }
        facc[rt][mt]=a;
      }
    }
    // online max + rescale
    #pragma unroll
    for (int rt=0;rt<2;++rt){
      #pragma unroll
      for (int j=0;j<4;++j){
        float cm = fmaxf(fmaxf(facc[rt][0][j],facc[rt][1][j]),fmaxf(facc[rt][2][j],facc[rt][3][j]));
        cm = fmaxf(cm, __shfl_xor(cm,1,64));
        cm = fmaxf(cm, __shfl_xor(cm,2,64));
        cm = fmaxf(cm, __shfl_xor(cm,4,64));
        cm = fmaxf(cm, __shfl_xor(cm,8,64));
        float nm = fmaxf(mx[rt][j], cm);
        float fac = __expf(mx[rt][j]-nm);
        mx[rt][j]=nm;
        dp[rt][j]*=fac;
        #pragma unroll
        for (int ct=0;ct<4;++ct) acc2[rt][ct][j]*=fac;
      }
    }
    // exp -> qpL, dp accumulation
    #pragma unroll
    for (int rt=0;rt<2;++rt){
      #pragma unroll
      for (int mt=0;mt<4;++mt){
        #pragma unroll
        for (int j=0;j<4;++j){
          int rl = w*32 + rt*16 + rowg + j;
          float vq = __expf(facc[rt][mt][j] - diag[rl] - mx[rt][j]);
          u16 us = f2bf(vq);
          qpL[rl*72 + mt*16 + fr] = us;
          dp[rt][j] += bf2f(us)*sK[mc*64 + mt*16 + fr];
        }
      }
    }
    __syncthreads();  // qpL visible (also drains prefetch)
    // PV: acc2 += qpL @ sCt^T
    #pragma unroll
    for (int rt=0;rt<2;++rt){
      #pragma unroll
      for (int ct=0;ct<4;++ct){
        #pragma unroll
        for (int kc=0;kc<2;++kc){
          bf16x8 av = *(const bf16x8*)&qpL[(w*32+rt*16+fr)*72 + kc*32 + kb];
          bf16x8 bv = *(const bf16x8*)&sCt[cur][(ct*16+fr)*64 + kc*32 + kb];
          acc2[rt][ct] = MFMA16(av,bv,acc2[rt][ct]);
        }
      }
    }
    __syncthreads();  // qpL free for next chunk
  }
  // dp reduce across fr lanes
  #pragma unroll
  for (int rt=0;rt<2;++rt){
    #pragma unroll
    for (int j=0;j<4;++j){
      dp[rt][j] += __shfl_xor(dp[rt][j],1,64);
      dp[rt][j] += __shfl_xor(dp[rt][j],2,64);
      dp[rt][j] += __shfl_xor(dp[rt][j],4,64);
      dp[rt][j] += __shfl_xor(dp[rt][j],8,64);
    }
  }
  float kss = kcssum[bh];
  const float eps=1e-4f;
  #pragma unroll
  for (int rt=0;rt<2;++rt){
    #pragma unroll
    for (int ct=0;ct<4;++ct){
      int d = ct*16 + fr;
      float cs = ctxsum[bh*64 + d];
      #pragma unroll
      for (int j=0;j<4;++j){
        int row = t0 + w*32 + rt*16 + rowg + j;
        float numer = acc2[rt][ct][j] + eps*cs;
        float den   = dp[rt][j] + eps*kss;
        outc[(size_t)row*512 + h*64 + d] = f2bf(numer/den);
      }
    }
  }
}

extern "C" void kernel_launch(void* const* d_in, const int* in_sizes, int n_in,
                              void* d_out, int out_size, void* d_ws, size_t ws_size,
                              hipStream_t stream)
{
  (void)in_sizes; (void)n_in; (void)out_size; (void)ws_size;
  const float* x    = (const float*)d_in[0];
  const float* Wq   = (const float*)d_in[1];
  const float* bq   = (const float*)d_in[2];
  const float* Wk   = (const float*)d_in[3];
  const float* bk   = (const float*)d_in[4];
  const float* Wv   = (const float*)d_in[5];
  const float* bv   = (const float*)d_in[6];
  const float* Wo   = (const float*)d_in[7];
  const float* bo   = (const float*)d_in[8];
  const float* proj = (const float*)d_in[9];

  char* w = (char*)d_ws;
  size_t off=0;
  auto alloc=[&](size_t bytes)->char*{ char* p=w+off; off=(off+bytes+255)&~(size_t)255; return p; };
  u16*  xb   = (u16*)alloc(8192ull*512*2);
  u16*  qB   = (u16*)alloc(8192ull*512*2);
  u16*  kBf  = (u16*)alloc(8192ull*512*2);
  u16*  vB   = (u16*)alloc(8192ull*512*2);
  u16*  vT   = (u16*)alloc(32ull*64*2048*2);
  u16*  WqT  = (u16*)alloc(512ull*512*2);
  u16*  WkT  = (u16*)alloc(512ull*512*2);
  u16*  WvT  = (u16*)alloc(512ull*512*2);
  u16*  WoT  = (u16*)alloc(512ull*512*2);
  u16*  projS= (u16*)alloc(512ull*64*2);
  float* ctx = (float*)alloc(32ull*512*64*4);
  u16*  ctxT = (u16*)alloc(32ull*64*512*2);
  float* kcs = (float*)alloc(32ull*512*4);
  u32*  kmx  = (u32*)alloc(256);
  float* ctxs= (float*)alloc(32ull*64*4);
  float* kcss= (float*)alloc(32ull*4);
  u16*  outc = kBf;  // kBf dead after k_kpctx; reuse

  dim3 TB(256);
  k_init<<<dim3(256),TB,0,stream>>>(ctx,kcs,kmx,projS,proj,x,xb);
  k_trw<<<dim3(16,16,4),TB,0,stream>>>(Wq,Wk,Wv,Wo, WqT,WkT,WvT,WoT);
  k_gemm2<false><<<dim3(64,8,3),TB,0,stream>>>(xb, WqT,WkT,WvT, bq,bk,bv, qB,kBf,vB);
  k_trv<<<dim3(2,64,32),TB,0,stream>>>(vB, vT);
  k_kmax<<<dim3(16,8,4),TB,0,stream>>>(kBf, projS, kmx);
  k_kpctx<<<dim3(16,8,4),TB,0,stream>>>(kBf, projS, vT, kmx, ctx, kcs);
  k_trctx<<<dim3(16,2,32),TB,0,stream>>>(ctx, ctxT);
  k_sums<<<dim3(32),TB,0,stream>>>(ctxT, kcs, ctxs, kcss);
  k_qpout2<<<dim3(16,8,4),TB,0,stream>>>(qB, projS, kcs, ctxT, ctxs, kcss, outc);
  k_gemm2<true><<<dim3(64,8,1),TB,0,stream>>>(outc, WoT,WoT,WoT, bo,bo,bo,
                                              d_out,d_out,d_out);
}

// Round 5
// 166.172 us; speedup vs baseline: 2.5623x; 1.0566x over previous
//
#include <hip/hip_runtime.h>

typedef unsigned short u16;
typedef unsigned int   u32;
typedef __attribute__((ext_vector_type(8))) short bf16x8;
typedef __attribute__((ext_vector_type(4))) short s16x4;
typedef __attribute__((ext_vector_type(4))) float f32x4;

#define MFMA16(a,b,c) __builtin_amdgcn_mfma_f32_16x16x32_bf16((a),(b),(c),0,0,0)

__device__ __forceinline__ float bf2f(u16 u){ return __uint_as_float(((u32)u)<<16); }
__device__ __forceinline__ u16 f2bf(float f){
  u32 u = __float_as_uint(f);
  return (u16)((u + 0x7fffu + ((u>>16)&1u)) >> 16);
}
__device__ __forceinline__ u32 encf(float f){ u32 u=__float_as_uint(f); return (u&0x80000000u)? ~u : (u|0x80000000u); }
__device__ __forceinline__ float decf(u32 u){ return (u&0x80000000u)? __uint_as_float(u&0x7fffffffu) : __uint_as_float(~u); }

// async global->LDS, 16B per lane, LDS dest = wave-uniform base + lane*16
__device__ __forceinline__ void async_lds16(u16* lds, const u16* g){
  __builtin_amdgcn_global_load_lds((const __attribute__((address_space(1))) void*)g,
                                   (__attribute__((address_space(3))) void*)lds,
                                   16, 0, 0);
}

// stage ROWS x 64 bf16 from global (srcStride elems) into LDS padded to 72/row
template<int ROWS>
__device__ __forceinline__ void stage64(u16* dst, const u16* src, int srcStride, int tid){
  #pragma unroll
  for (int u=tid; u<ROWS*8; u+=256){
    int r=u>>3, c=(u&7)<<3;
    *(int4*)&dst[r*72+c] = *(const int4*)&src[(size_t)r*srcStride + c];
  }
}

// ---------------- init: zero kmax, projS = dn*proj (bf16), x -> bf16 ----------------
__global__ void k_init(u32* kmaxEnc, u16* projS,
                       const float* __restrict__ proj, const float* __restrict__ x, u16* __restrict__ xb){
  int i = blockIdx.x*blockDim.x + threadIdx.x;
  int st = gridDim.x*blockDim.x;
  for (int j=i; j<32; j+=st) kmaxEnc[j]=0u;
  const float dn = 0.35355339059327373f; // 64^-0.25
  for (int j=i; j<512*64; j+=st) projS[j] = f2bf(dn*proj[j]);
  for (int j=i; j<524288; j+=st){
    float4 a = *(const float4*)&x[(size_t)j*8];
    float4 b = *(const float4*)&x[(size_t)j*8+4];
    u16 tmp[8] = {f2bf(a.x),f2bf(a.y),f2bf(a.z),f2bf(a.w),
                  f2bf(b.x),f2bf(b.y),f2bf(b.z),f2bf(b.w)};
    *(int4*)&xb[(size_t)j*8] = *(const int4*)tmp;
  }
}

// ---------------- fp32 512x512 -> bf16 transpose, batched over 4 weights ----------------
__global__ __launch_bounds__(256) void k_trw(const float* s0, const float* s1, const float* s2, const float* s3,
                                             u16* d0, u16* d1, u16* d2, u16* d3){
  int z = blockIdx.z;
  const float* src = z==0?s0:(z==1?s1:(z==2?s2:s3));
  u16* dst         = z==0?d0:(z==1?d1:(z==2?d2:d3));
  __shared__ u16 t[32][34];
  int c0=blockIdx.x*32, r0=blockIdx.y*32;
  int tid=threadIdx.x;
  for (int u=tid; u<1024; u+=256){ int r=u>>5, c=u&31; t[r][c]=f2bf(src[(size_t)(r0+r)*512 + c0+c]); }
  __syncthreads();
  for (int u=tid; u<1024; u+=256){ int c=u>>5, r=u&31; dst[(size_t)(c0+c)*512 + r0+r]=t[r][c]; }
}

// ---------------- v (per b,h 2048x64 slice of [t][512]) -> vT[bh][64][2048] ----------------
__global__ __launch_bounds__(256) void k_trv(const u16* __restrict__ v, u16* __restrict__ vT){
  int bh = blockIdx.z; int b=bh>>3, h=bh&7;
  int d0 = blockIdx.x*32, n0 = blockIdx.y*32;
  __shared__ u16 t[32][34];
  int tid=threadIdx.x;
  const u16* s = v + (size_t)(b*2048)*512 + h*64;
  for (int u=tid; u<1024; u+=256){ int r=u>>5, c=u&31; t[r][c]=s[(size_t)(n0+r)*512 + d0+c]; }
  __syncthreads();
  u16* d = vT + (size_t)bh*64*2048;
  for (int u=tid; u<1024; u+=256){ int c=u>>5, r=u&31; d[(size_t)(d0+c)*2048 + n0+r]=t[r][c]; }
}

// ---------------- vsum[bh][d] = sum_n v[n][d] ----------------
__global__ __launch_bounds__(256) void k_vsum(const u16* __restrict__ vB, float* __restrict__ vsum){
  int bh=blockIdx.x; int b=bh>>3, h=bh&7;
  int tid=threadIdx.x; int d=tid&63, part=tid>>6;
  const u16* src = vB + (size_t)(b*2048 + part*512)*512 + h*64 + d;
  float s=0.f;
  for (int n=0;n<512;++n) s += bf2f(src[(size_t)n*512]);
  __shared__ float red[256];
  red[tid]=s; __syncthreads();
  if (part==0) vsum[bh*64+d]=red[d]+red[64+d]+red[128+d]+red[192+d];
}

// ---------------- per-bh sums: Csum[d] = sum_m ctxT[d][m]; Ssum = sum_m S[m] ----------------
__global__ __launch_bounds__(256) void k_sums(const u16* __restrict__ ctxT, const float* __restrict__ kcs,
                                              float* __restrict__ ctxsum, float* __restrict__ kcssum){
  int bh = blockIdx.x;
  int tid = threadIdx.x;
  int d = tid&63, part = tid>>6;
  const u16* src = ctxT + (size_t)bh*64*512 + (size_t)d*512 + part*128;
  float s=0.f;
  for (int m=0;m<128;m+=8){
    bf16x8 v = *(const bf16x8*)&src[m];
    #pragma unroll
    for (int j=0;j<8;++j) s += bf2f((u16)v[j]);
  }
  __shared__ float red[256];
  __shared__ float red2[256];
  red[tid]=s;
  float t=0.f;
  for (int u=tid;u<512;u+=256) t += kcs[(size_t)bh*512+u];
  red2[tid]=t;
  __syncthreads();
  if (part==0) ctxsum[bh*64+d] = red[d]+red[64+d]+red[128+d]+red[192+d];
  if (tid<64){
    float a=red2[tid]+red2[tid+64]+red2[tid+128]+red2[tid+192];
    #pragma unroll
    for (int m2=1;m2<64;m2<<=1) a += __shfl_xor(a,m2,64);
    if (tid==0) kcssum[bh]=a;
  }
}

// ---------------- GEMM m97-style: O[8192x512] = A(bf16) @ BT^T + bias ----------------
template<bool OF32>
__global__ __launch_bounds__(256) void k_gemm2(const u16* __restrict__ A,
    const u16* BT0, const u16* BT1, const u16* BT2,
    const float* b0, const float* b1, const float* b2,
    void* O0, void* O1, void* O2)
{
  int z = blockIdx.z;
  const u16* BT    = z==0?BT0:(z==1?BT1:BT2);
  const float* bias= z==0?b0 :(z==1?b1 :b2 );
  void* Ov         = z==0?O0 :(z==1?O1 :O2 );
  int bm = blockIdx.x*128, bn = blockIdx.y*64;
  __shared__ u16 sA[128*64];
  __shared__ u16 sB[64*64];
  int tid=threadIdx.x, w=tid>>6, lane=tid&63;
  int lr = lane>>3, lc = (lane&7)*8;
  f32x4 acc[8] = {};
  for (int kk=0; kk<512; kk+=64){
    __syncthreads();
    #pragma unroll
    for (int i=0;i<4;++i){
      int idx = w*4+i;
      async_lds16(&sA[idx*512], A + (size_t)(bm + idx*8 + lr)*512 + kk + lc);
    }
    #pragma unroll
    for (int i=0;i<2;++i){
      int idx = w*2+i;
      async_lds16(&sB[idx*512], BT + (size_t)(bn + idx*8 + lr)*512 + kk + lc);
    }
    __syncthreads();
    int fr = lane&15, kb=(lane>>4)*8;
    #pragma unroll
    for (int rt=0; rt<2; ++rt){
      int ar = (w*2+rt)*16 + fr;
      #pragma unroll
      for (int ct=0; ct<4; ++ct){
        int br = ct*16 + fr;
        #pragma unroll
        for (int kc=0; kc<2; ++kc){
          bf16x8 av = *(const bf16x8*)&sA[ar*64 + kc*32 + kb];
          bf16x8 bv = *(const bf16x8*)&sB[br*64 + kc*32 + kb];
          acc[rt*4+ct] = MFMA16(av,bv,acc[rt*4+ct]);
        }
      }
    }
  }
  int colg = lane&15, rowg=(lane>>4)*4;
  #pragma unroll
  for (int rt=0; rt<2; ++rt){
    #pragma unroll
    for (int ct=0; ct<4; ++ct){
      int col = bn + ct*16 + colg;
      float bv = bias[col];
      #pragma unroll
      for (int j=0;j<4;++j){
        int row = bm + (w*2+rt)*16 + rowg + j;
        if constexpr (OF32) ((float*)Ov)[(size_t)row*512 + col] = acc[rt*4+ct][j] + bv;
        else                ((u16*) Ov)[(size_t)row*512 + col] = f2bf(acc[rt*4+ct][j] + bv);
      }
    }
  }
}

// ---------------- k features (exp-only) + full-n ctx + S + mk : NO atomics on data ----------------
// block = (m-tile of 64, h, b); loops all 16 n-chunks of 128.
__global__ __launch_bounds__(256) void k_kpctx2(const u16* __restrict__ kB, const u16* __restrict__ projS,
    const u16* __restrict__ vT, u16* __restrict__ ctxT, float* __restrict__ kcs, u32* __restrict__ kmaxEnc)
{
  int mblk=blockIdx.x, h=blockIdx.y, b=blockIdx.z;
  int bh=b*8+h;
  int m0 = mblk*64;
  __shared__ u16 sK[128*72];
  __shared__ u16 sV[64*136];
  __shared__ u16 sP[64*72];
  __shared__ u16 sT[64*136];
  __shared__ float diag[128];
  __shared__ float red[4];
  int tid=threadIdx.x, w=tid>>6, lane=tid&63;
  int fr=lane&15, kb=(lane>>4)*8, rowg=(lane>>4)*4;
  stage64<64>(sP, projS + m0*64, 64, tid);
  f32x4 accc[4]={};          // ctx acc: m = w*16+rowg+j, d = ct*16+fr
  float sS=0.f;              // kcs quarter-partial for (m=tid>>2, q=tid&3)
  float lm=-3.0e38f;
  const u16* gK = kB + (size_t)(b*2048)*512 + h*64;
  const u16* gV = vT + (size_t)bh*64*2048;
  int4 pK[4], pV[4];
  #pragma unroll
  for (int i=0;i<4;++i){ int u=tid+i*256; int r=u>>3,c=(u&7)<<3; pK[i]=*(const int4*)&gK[(size_t)r*512 + c]; }
  #pragma unroll
  for (int i=0;i<4;++i){ int u=tid+i*256; int r=u>>4,c=(u&15)<<3; pV[i]=*(const int4*)&gV[(size_t)r*2048 + c]; }
  for (int nc=0; nc<16; ++nc){
    // phase 1: write staged regs to padded LDS
    #pragma unroll
    for (int i=0;i<4;++i){ int u=tid+i*256; int r=u>>3,c=(u&7)<<3; *(int4*)&sK[r*72+c]=pK[i]; }
    #pragma unroll
    for (int i=0;i<4;++i){ int u=tid+i*256; int r=u>>4,c=(u&15)<<3; *(int4*)&sV[r*136+c]=pV[i]; }
    __syncthreads();
    // phase 2: diag + feature MFMA dd[128 n][64 m]
    if (tid<128){
      float s=0.f;
      #pragma unroll
      for (int c=0;c<64;c+=8){
        bf16x8 v=*(const bf16x8*)&sK[tid*72+c];
        #pragma unroll
        for (int j=0;j<8;++j){ float f=bf2f((u16)v[j]); s+=f*f; }
      }
      diag[tid]=0.0625f*s; // 0.5*dn^2
    }
    f32x4 facc[2][4];
    #pragma unroll
    for (int rt=0;rt<2;++rt){
      int ar=(w*2+rt)*16+fr;
      #pragma unroll
      for (int mt=0;mt<4;++mt){
        f32x4 a={0.f,0.f,0.f,0.f};
        a=MFMA16(*(const bf16x8*)&sK[ar*72+kb],    *(const bf16x8*)&sP[(mt*16+fr)*72+kb],    a);
        a=MFMA16(*(const bf16x8*)&sK[ar*72+32+kb], *(const bf16x8*)&sP[(mt*16+fr)*72+32+kb], a);
        facc[rt][mt]=a;
        lm=fmaxf(lm, fmaxf(fmaxf(a[0],a[1]),fmaxf(a[2],a[3])));
      }
    }
    __syncthreads();
    // phase 3: exp -> sT[m][n]  (exp-only: no ratio, no eps, no max)
    #pragma unroll
    for (int rt=0;rt<2;++rt){
      int rbase=(w*2+rt)*16;
      int nl = rbase + rowg;
      #pragma unroll
      for (int mt=0;mt<4;++mt){
        int ml = mt*16 + fr;
        s16x4 pk;
        #pragma unroll
        for (int j=0;j<4;++j){
          float vk = __expf(facc[rt][mt][j] - diag[nl+j]);
          pk[j]=(short)f2bf(vk);
        }
        *(s16x4*)&sT[ml*136 + nl] = pk;
      }
    }
    __syncthreads();
    // phase 4: prefetch next chunk + PV MFMA + S partial
    if (nc<15){
      #pragma unroll
      for (int i=0;i<4;++i){ int u=tid+i*256; int r=u>>3,c=(u&7)<<3; pK[i]=*(const int4*)&gK[(size_t)((nc+1)*128+r)*512 + c]; }
      #pragma unroll
      for (int i=0;i<4;++i){ int u=tid+i*256; int r=u>>4,c=(u&15)<<3; pV[i]=*(const int4*)&gV[(size_t)r*2048 + (nc+1)*128 + c]; }
    }
    int am = w*16 + fr;
    #pragma unroll
    for (int ct=0;ct<4;++ct){
      #pragma unroll
      for (int ks=0;ks<4;++ks){
        accc[ct]=MFMA16(*(const bf16x8*)&sT[am*136+ks*32+kb],
                        *(const bf16x8*)&sV[(ct*16+fr)*136+ks*32+kb], accc[ct]);
      }
    }
    {
      int m=tid>>2, q=tid&3;
      float s=0.f;
      #pragma unroll
      for (int n=0;n<32;++n) s += bf2f(sT[m*136 + q*32 + n]);
      sS += s;
    }
    __syncthreads();
  }
  // S store (no atomics)
  {
    int m=tid>>2, q=tid&3;
    float s = sS;
    s += __shfl_xor(s,1,64); s += __shfl_xor(s,2,64);
    if (q==0) kcs[(size_t)bh*512 + m0 + m] = s;
  }
  // mk
  #pragma unroll
  for (int m2=1;m2<64;m2<<=1) lm = fmaxf(lm, __shfl_xor(lm,m2,64));
  if (lane==0) red[w]=lm;
  __syncthreads();
  if (tid==0) atomicMax(&kmaxEnc[bh], encf(fmaxf(fmaxf(red[0],red[1]),fmaxf(red[2],red[3]))));
  // ctxT tile via LDS bounce (sT reused as [64 d][72])
  int mloc = w*16 + rowg;
  #pragma unroll
  for (int ct=0;ct<4;++ct){
    #pragma unroll
    for (int j=0;j<4;++j) sT[(ct*16+fr)*72 + mloc + j] = f2bf(accc[ct][j]);
  }
  __syncthreads();
  for (int u=tid; u<512; u+=256){
    int r=u>>3, c=(u&7)<<3;
    *(int4*)&ctxT[(size_t)(bh*64+r)*512 + m0 + c] = *(const int4*)&sT[r*72+c];
  }
}

// ---------------- q features (exp-only) + PV + exact eps epilogue ----------------
__global__ __launch_bounds__(256) void k_qpout2(const u16* __restrict__ qB, const u16* __restrict__ projS,
    const float* __restrict__ kcs, const u16* __restrict__ ctxT,
    const float* __restrict__ ctxsum, const float* __restrict__ kcssum,
    const float* __restrict__ vsum, const u32* __restrict__ kmaxEnc,
    u16* __restrict__ outc)
{
  int chunk=blockIdx.x, h=blockIdx.y, b=blockIdx.z;
  int bh=b*8+h;
  int t0 = b*2048 + chunk*128;
  __shared__ u16 sP[2][64*64];
  __shared__ u16 sCt[2][64*64];
  __shared__ u16 qpL[128*72];
  __shared__ float sK[512];
  __shared__ float diag[128];
  int tid=threadIdx.x, w=tid>>6, lane=tid&63;
  int fr=lane&15, kb=(lane>>4)*8, rowg=(lane>>4)*4;
  bf16x8 qf[2][2];
  #pragma unroll
  for (int rt=0;rt<2;++rt)
    #pragma unroll
    for (int kc=0;kc<2;++kc)
      qf[rt][kc] = *(const bf16x8*)&qB[(size_t)(t0 + w*32 + rt*16 + fr)*512 + h*64 + kc*32 + kb];
  #pragma unroll
  for (int rt=0;rt<2;++rt){
    float s=0.f;
    #pragma unroll
    for (int kc=0;kc<2;++kc)
      #pragma unroll
      for (int j=0;j<8;++j){ float f=bf2f((u16)qf[rt][kc][j]); s+=f*f; }
    s += __shfl_xor(s,16,64); s += __shfl_xor(s,32,64);
    if (lane<16) diag[w*32 + rt*16 + fr] = 0.0625f*s;
  }
  for (int u=tid; u<512; u+=256) sK[u] = kcs[(size_t)bh*512 + u];
  {
    const u16* gp = projS;
    const u16* gc = ctxT + (size_t)bh*64*512;
    int lr=lane>>3, lc=(lane&7)*8;
    #pragma unroll
    for (int i=0;i<2;++i){
      int idx = w*2+i;
      async_lds16(&sP[0][idx*512], gp + idx*512 + lane*8);
      async_lds16(&sCt[0][idx*512], gc + (size_t)(idx*8+lr)*512 + lc);
    }
  }
  f32x4 acc2[2][4]={};
  float mx[2][4], dp[2][4], rs[2][4];
  #pragma unroll
  for (int rt=0;rt<2;++rt)
    #pragma unroll
    for (int j=0;j<4;++j){ mx[rt][j]=-3.0e38f; dp[rt][j]=0.f; rs[rt][j]=0.f; }
  __syncthreads();
  for (int mc=0; mc<8; ++mc){
    int cur = mc&1;
    if (mc<7){
      int nxt = cur^1;
      const u16* gp = projS + (mc+1)*64*64;
      const u16* gc = ctxT + (size_t)bh*64*512 + (mc+1)*64;
      int lr=lane>>3, lc=(lane&7)*8;
      #pragma unroll
      for (int i=0;i<2;++i){
        int idx = w*2+i;
        async_lds16(&sP[nxt][idx*512], gp + idx*512 + lane*8);
        async_lds16(&sCt[nxt][idx*512], gc + (size_t)(idx*8+lr)*512 + lc);
      }
    }
    f32x4 facc[2][4];
    #pragma unroll
    for (int rt=0;rt<2;++rt){
      #pragma unroll
      for (int mt=0;mt<4;++mt){
        f32x4 a={0.f,0.f,0.f,0.f};
        #pragma unroll
        for (int kc=0;kc<2;++kc){
          bf16x8 bv = *(const bf16x8*)&sP[cur][(mt*16+fr)*64 + kc*32 + kb];
          a = MFMA16(qf[rt][kc], bv, a);
        }
        facc[rt][mt]=a;
      }
    }
    // exp-only qp; track running max (for eps term only — no rescale needed)
    #pragma unroll
    for (int rt=0;rt<2;++rt){
      #pragma unroll
      for (int mt=0;mt<4;++mt){
        #pragma unroll
        for (int j=0;j<4;++j){
          int rl = w*32 + rt*16 + rowg + j;
          mx[rt][j] = fmaxf(mx[rt][j], facc[rt][mt][j]);
          float vq = __expf(facc[rt][mt][j] - diag[rl]);
          u16 us = f2bf(vq);
          qpL[rl*72 + mt*16 + fr] = us;
          float uf = bf2f(us);
          dp[rt][j] += uf*sK[mc*64 + mt*16 + fr];
          rs[rt][j] += uf;
        }
      }
    }
    __syncthreads();
    #pragma unroll
    for (int rt=0;rt<2;++rt){
      #pragma unroll
      for (int ct=0;ct<4;++ct){
        #pragma unroll
        for (int kc=0;kc<2;++kc){
          bf16x8 av = *(const bf16x8*)&qpL[(w*32+rt*16+fr)*72 + kc*32 + kb];
          bf16x8 bv = *(const bf16x8*)&sCt[cur][(ct*16+fr)*64 + kc*32 + kb];
          acc2[rt][ct] = MFMA16(av,bv,acc2[rt][ct]);
        }
      }
    }
    __syncthreads();
  }
  #pragma unroll
  for (int rt=0;rt<2;++rt){
    #pragma unroll
    for (int j=0;j<4;++j){
      #pragma unroll
      for (int s=1;s<16;s<<=1){
        dp[rt][j] += __shfl_xor(dp[rt][j],s,64);
        rs[rt][j] += __shfl_xor(rs[rt][j],s,64);
        mx[rt][j]  = fmaxf(mx[rt][j], __shfl_xor(mx[rt][j],s,64));
      }
    }
  }
  float mk  = decf(kmaxEnc[bh]);
  float emk = __expf(mk);
  float Ssum = kcssum[bh];
  const float eps=1e-4f;
  float emq[2][4];
  #pragma unroll
  for (int rt=0;rt<2;++rt)
    #pragma unroll
    for (int j=0;j<4;++j) emq[rt][j]=__expf(mx[rt][j]);
  #pragma unroll
  for (int rt=0;rt<2;++rt){
    #pragma unroll
    for (int ct=0;ct<4;++ct){
      int d = ct*16 + fr;
      float cs = ctxsum[bh*64 + d];
      float vs = vsum[bh*64 + d];
      #pragma unroll
      for (int j=0;j<4;++j){
        float eq = emq[rt][j];
        float numer = acc2[rt][ct][j] + eps*(emk*vs*rs[rt][j] + eq*cs + eps*eq*emk*512.0f*vs);
        float den   = dp[rt][j]       + eps*(emk*2048.0f*rs[rt][j] + eq*Ssum + eps*eq*emk*512.0f*2048.0f);
        int row = t0 + w*32 + rt*16 + rowg + j;
        outc[(size_t)row*512 + h*64 + d] = f2bf(numer/den);
      }
    }
  }
}

extern "C" void kernel_launch(void* const* d_in, const int* in_sizes, int n_in,
                              void* d_out, int out_size, void* d_ws, size_t ws_size,
                              hipStream_t stream)
{
  (void)in_sizes; (void)n_in; (void)out_size; (void)ws_size;
  const float* x    = (const float*)d_in[0];
  const float* Wq   = (const float*)d_in[1];
  const float* bq   = (const float*)d_in[2];
  const float* Wk   = (const float*)d_in[3];
  const float* bk   = (const float*)d_in[4];
  const float* Wv   = (const float*)d_in[5];
  const float* bv   = (const float*)d_in[6];
  const float* Wo   = (const float*)d_in[7];
  const float* bo   = (const float*)d_in[8];
  const float* proj = (const float*)d_in[9];

  char* w = (char*)d_ws;
  size_t off=0;
  auto alloc=[&](size_t bytes)->char*{ char* p=w+off; off=(off+bytes+255)&~(size_t)255; return p; };
  u16*  xb   = (u16*)alloc(8192ull*512*2);
  u16*  qB   = (u16*)alloc(8192ull*512*2);
  u16*  kBf  = (u16*)alloc(8192ull*512*2);
  u16*  vB   = (u16*)alloc(8192ull*512*2);
  u16*  vT   = (u16*)alloc(32ull*64*2048*2);
  u16*  WqT  = (u16*)alloc(512ull*512*2);
  u16*  WkT  = (u16*)alloc(512ull*512*2);
  u16*  WvT  = (u16*)alloc(512ull*512*2);
  u16*  WoT  = (u16*)alloc(512ull*512*2);
  u16*  projS= (u16*)alloc(512ull*64*2);
  u16*  ctxT = (u16*)alloc(32ull*64*512*2);
  float* kcs = (float*)alloc(32ull*512*4);
  u32*  kmx  = (u32*)alloc(256);
  float* ctxs= (float*)alloc(32ull*64*4);
  float* kcss= (float*)alloc(32ull*4);
  float* vsm = (float*)alloc(32ull*64*4);
  u16*  outc = kBf;  // kBf dead after k_kpctx2; reuse

  dim3 TB(256);
  k_init<<<dim3(256),TB,0,stream>>>(kmx,projS,proj,x,xb);
  k_trw<<<dim3(16,16,4),TB,0,stream>>>(Wq,Wk,Wv,Wo, WqT,WkT,WvT,WoT);
  k_gemm2<false><<<dim3(64,8,3),TB,0,stream>>>(xb, WqT,WkT,WvT, bq,bk,bv, qB,kBf,vB);
  k_trv<<<dim3(2,64,32),TB,0,stream>>>(vB, vT);
  k_vsum<<<dim3(32),TB,0,stream>>>(vB, vsm);
  k_kpctx2<<<dim3(8,8,4),TB,0,stream>>>(kBf, projS, vT, ctxT, kcs, kmx);
  k_sums<<<dim3(32),TB,0,stream>>>(ctxT, kcs, ctxs, kcss);
  k_qpout2<<<dim3(16,8,4),TB,0,stream>>>(qB, projS, kcs, ctxT, ctxs, kcss, vsm, kmx, outc);
  k_gemm2<true><<<dim3(64,8,1),TB,0,stream>>>(outc, WoT,WoT,WoT, bo,bo,bo,
                                              d_out,d_out,d_out);
}

// Round 6
// 157.261 us; speedup vs baseline: 2.7075x; 1.0567x over previous
//
#include <hip/hip_runtime.h>

typedef unsigned short u16;
typedef unsigned int   u32;
typedef __attribute__((ext_vector_type(8))) short bf16x8;
typedef __attribute__((ext_vector_type(4))) short s16x4;
typedef __attribute__((ext_vector_type(4))) float f32x4;

#define MFMA16(a,b,c) __builtin_amdgcn_mfma_f32_16x16x32_bf16((a),(b),(c),0,0,0)

__device__ __forceinline__ float bf2f(u16 u){ return __uint_as_float(((u32)u)<<16); }
__device__ __forceinline__ u16 f2bf(float f){
  u32 u = __float_as_uint(f);
  return (u16)((u + 0x7fffu + ((u>>16)&1u)) >> 16);
}
__device__ __forceinline__ u32 encf(float f){ u32 u=__float_as_uint(f); return (u&0x80000000u)? ~u : (u|0x80000000u); }
__device__ __forceinline__ float decf(u32 u){ return (u&0x80000000u)? __uint_as_float(u&0x7fffffffu) : __uint_as_float(~u); }

// async global->LDS, 16B per lane, LDS dest = wave-uniform base + lane*16
__device__ __forceinline__ void async_lds16(u16* lds, const u16* g){
  __builtin_amdgcn_global_load_lds((const __attribute__((address_space(1))) void*)g,
                                   (__attribute__((address_space(3))) void*)lds,
                                   16, 0, 0);
}

// stage ROWS x 64 bf16 from global (srcStride elems) into LDS padded to 72/row
template<int ROWS>
__device__ __forceinline__ void stage64(u16* dst, const u16* src, int srcStride, int tid){
  #pragma unroll
  for (int u=tid; u<ROWS*8; u+=256){
    int r=u>>3, c=(u&7)<<3;
    *(int4*)&dst[r*72+c] = *(const int4*)&src[(size_t)r*srcStride + c];
  }
}

// ---------------- init: zero kmax, projS = dn*proj (bf16), x -> bf16 ----------------
__global__ void k_init(u32* kmaxEnc, u16* projS,
                       const float* __restrict__ proj, const float* __restrict__ x, u16* __restrict__ xb){
  int i = blockIdx.x*blockDim.x + threadIdx.x;
  int st = gridDim.x*blockDim.x;
  for (int j=i; j<32; j+=st) kmaxEnc[j]=0u;
  const float dn = 0.35355339059327373f; // 64^-0.25
  for (int j=i; j<512*64; j+=st) projS[j] = f2bf(dn*proj[j]);
  for (int j=i; j<524288; j+=st){
    float4 a = *(const float4*)&x[(size_t)j*8];
    float4 b = *(const float4*)&x[(size_t)j*8+4];
    u16 tmp[8] = {f2bf(a.x),f2bf(a.y),f2bf(a.z),f2bf(a.w),
                  f2bf(b.x),f2bf(b.y),f2bf(b.z),f2bf(b.w)};
    *(int4*)&xb[(size_t)j*8] = *(const int4*)tmp;
  }
}

// ---------------- fp32 512x512 -> bf16 transpose, batched over 4 weights ----------------
__global__ __launch_bounds__(256) void k_trw(const float* s0, const float* s1, const float* s2, const float* s3,
                                             u16* d0, u16* d1, u16* d2, u16* d3){
  int z = blockIdx.z;
  const float* src = z==0?s0:(z==1?s1:(z==2?s2:s3));
  u16* dst         = z==0?d0:(z==1?d1:(z==2?d2:d3));
  __shared__ u16 t[32][34];
  int c0=blockIdx.x*32, r0=blockIdx.y*32;
  int tid=threadIdx.x;
  for (int u=tid; u<1024; u+=256){ int r=u>>5, c=u&31; t[r][c]=f2bf(src[(size_t)(r0+r)*512 + c0+c]); }
  __syncthreads();
  for (int u=tid; u<1024; u+=256){ int c=u>>5, r=u&31; dst[(size_t)(c0+c)*512 + r0+r]=t[r][c]; }
}

// ---------------- v (per b,h 2048x64 slice of [t][512]) -> vT[bh][64][2048] ----------------
__global__ __launch_bounds__(256) void k_trv(const u16* __restrict__ v, u16* __restrict__ vT){
  int bh = blockIdx.z; int b=bh>>3, h=bh&7;
  int d0 = blockIdx.x*32, n0 = blockIdx.y*32;
  __shared__ u16 t[32][34];
  int tid=threadIdx.x;
  const u16* s = v + (size_t)(b*2048)*512 + h*64;
  for (int u=tid; u<1024; u+=256){ int r=u>>5, c=u&31; t[r][c]=s[(size_t)(n0+r)*512 + d0+c]; }
  __syncthreads();
  u16* d = vT + (size_t)bh*64*2048;
  for (int u=tid; u<1024; u+=256){ int c=u>>5, r=u&31; d[(size_t)(d0+c)*2048 + n0+r]=t[r][c]; }
}

// ---------------- vsum[bh][d] = sum_n v[n][d] ----------------
__global__ __launch_bounds__(256) void k_vsum(const u16* __restrict__ vB, float* __restrict__ vsum){
  int bh=blockIdx.x; int b=bh>>3, h=bh&7;
  int tid=threadIdx.x; int d=tid&63, part=tid>>6;
  const u16* src = vB + (size_t)(b*2048 + part*512)*512 + h*64 + d;
  float s=0.f;
  for (int n=0;n<512;++n) s += bf2f(src[(size_t)n*512]);
  __shared__ float red[256];
  red[tid]=s; __syncthreads();
  if (part==0) vsum[bh*64+d]=red[d]+red[64+d]+red[128+d]+red[192+d];
}

// ---------------- diagK[bh][n] = 0.0625 * sum_k k[n][k]^2 (computed ONCE) ----------------
__global__ __launch_bounds__(256) void k_kdiag(const u16* __restrict__ kB, float* __restrict__ diagK){
  int bh=blockIdx.x, seg=blockIdx.y;
  int b=bh>>3, h=bh&7;
  int tid=threadIdx.x;
  int part=tid&7;
  const u16* base = kB + (size_t)(b*2048 + seg*256)*512 + h*64 + part*8;
  for (int n0=0; n0<256; n0+=32){
    int n = n0 + (tid>>3);
    bf16x8 v = *(const bf16x8*)&base[(size_t)n*512];
    float sq=0.f;
    #pragma unroll
    for (int j=0;j<8;++j){ float f=bf2f((u16)v[j]); sq+=f*f; }
    sq += __shfl_xor(sq,1,64); sq += __shfl_xor(sq,2,64); sq += __shfl_xor(sq,4,64);
    if (part==0) diagK[(size_t)bh*2048 + seg*256 + n] = 0.0625f*sq;
  }
}

// ---------------- per-bh sums: Csum[d] = sum_m ctxT[d][m]; Ssum = sum_m S[m] ----------------
__global__ __launch_bounds__(256) void k_sums(const u16* __restrict__ ctxT, const float* __restrict__ kcs,
                                              float* __restrict__ ctxsum, float* __restrict__ kcssum){
  int bh = blockIdx.x;
  int tid = threadIdx.x;
  int d = tid&63, part = tid>>6;
  const u16* src = ctxT + (size_t)bh*64*512 + (size_t)d*512 + part*128;
  float s=0.f;
  for (int m=0;m<128;m+=8){
    bf16x8 v = *(const bf16x8*)&src[m];
    #pragma unroll
    for (int j=0;j<8;++j) s += bf2f((u16)v[j]);
  }
  __shared__ float red[256];
  __shared__ float red2[256];
  red[tid]=s;
  float t=0.f;
  for (int u=tid;u<512;u+=256) t += kcs[(size_t)bh*512+u];
  red2[tid]=t;
  __syncthreads();
  if (part==0) ctxsum[bh*64+d] = red[d]+red[64+d]+red[128+d]+red[192+d];
  if (tid<64){
    float a=red2[tid]+red2[tid+64]+red2[tid+128]+red2[tid+192];
    #pragma unroll
    for (int m2=1;m2<64;m2<<=1) a += __shfl_xor(a,m2,64);
    if (tid==0) kcssum[bh]=a;
  }
}

// ---------------- GEMM m97-style: O[8192x512] = A(bf16) @ BT^T + bias ----------------
template<bool OF32>
__global__ __launch_bounds__(256) void k_gemm2(const u16* __restrict__ A,
    const u16* BT0, const u16* BT1, const u16* BT2,
    const float* b0, const float* b1, const float* b2,
    void* O0, void* O1, void* O2)
{
  int z = blockIdx.z;
  const u16* BT    = z==0?BT0:(z==1?BT1:BT2);
  const float* bias= z==0?b0 :(z==1?b1 :b2 );
  void* Ov         = z==0?O0 :(z==1?O1 :O2 );
  int bm = blockIdx.x*128, bn = blockIdx.y*64;
  __shared__ u16 sA[128*64];
  __shared__ u16 sB[64*64];
  int tid=threadIdx.x, w=tid>>6, lane=tid&63;
  int lr = lane>>3, lc = (lane&7)*8;
  f32x4 acc[8] = {};
  for (int kk=0; kk<512; kk+=64){
    __syncthreads();
    #pragma unroll
    for (int i=0;i<4;++i){
      int idx = w*4+i;
      async_lds16(&sA[idx*512], A + (size_t)(bm + idx*8 + lr)*512 + kk + lc);
    }
    #pragma unroll
    for (int i=0;i<2;++i){
      int idx = w*2+i;
      async_lds16(&sB[idx*512], BT + (size_t)(bn + idx*8 + lr)*512 + kk + lc);
    }
    __syncthreads();
    int fr = lane&15, kb=(lane>>4)*8;
    #pragma unroll
    for (int rt=0; rt<2; ++rt){
      int ar = (w*2+rt)*16 + fr;
      #pragma unroll
      for (int ct=0; ct<4; ++ct){
        int br = ct*16 + fr;
        #pragma unroll
        for (int kc=0; kc<2; ++kc){
          bf16x8 av = *(const bf16x8*)&sA[ar*64 + kc*32 + kb];
          bf16x8 bv = *(const bf16x8*)&sB[br*64 + kc*32 + kb];
          acc[rt*4+ct] = MFMA16(av,bv,acc[rt*4+ct]);
        }
      }
    }
  }
  int colg = lane&15, rowg=(lane>>4)*4;
  #pragma unroll
  for (int rt=0; rt<2; ++rt){
    #pragma unroll
    for (int ct=0; ct<4; ++ct){
      int col = bn + ct*16 + colg;
      float bv = bias[col];
      #pragma unroll
      for (int j=0;j<4;++j){
        int row = bm + (w*2+rt)*16 + rowg + j;
        if constexpr (OF32) ((float*)Ov)[(size_t)row*512 + col] = acc[rt*4+ct][j] + bv;
        else                ((u16*) Ov)[(size_t)row*512 + col] = f2bf(acc[rt*4+ct][j] + bv);
      }
    }
  }
}

// ---------------- k features (exp-only) + half-n ctx partial + S partial + mk ----------------
// grid (8 h, 16 = s*8+mblk, 4 b): blockIdx.x = h -> all blocks of head h share an XCD L2.
__global__ __launch_bounds__(256) void k_kpctx3(const u16* __restrict__ kB, const u16* __restrict__ projS,
    const u16* __restrict__ vT, const float* __restrict__ diagK,
    float* __restrict__ ctxPT, float* __restrict__ kcsP, u32* __restrict__ kmaxEnc)
{
  int h=blockIdx.x, y=blockIdx.y, b=blockIdx.z;
  int mblk = y&7, s = y>>3;
  int bh=b*8+h;
  int m0 = mblk*64;
  __shared__ __align__(16) u16 sK[128*72];
  __shared__ __align__(16) u16 sV[64*136];
  __shared__ __align__(16) u16 sP[64*72];
  __shared__ __align__(16) u16 sT[64*136];
  __shared__ float sDg[128];
  __shared__ float red[4];
  int tid=threadIdx.x, w=tid>>6, lane=tid&63;
  int fr=lane&15, kb=(lane>>4)*8, rowg=(lane>>4)*4;
  stage64<64>(sP, projS + m0*64, 64, tid);
  f32x4 accc[4]={};
  float sS=0.f;
  float lm=-3.0e38f;
  const u16* gK = kB + (size_t)(b*2048 + s*1024)*512 + h*64;
  const u16* gV = vT + (size_t)bh*64*2048 + s*1024;
  const float* gD = diagK + (size_t)bh*2048 + s*1024;
  int4 pK[4], pV[4]; float4 pD={0.f,0.f,0.f,0.f};
  #pragma unroll
  for (int i=0;i<4;++i){ int u=tid+i*256; int r=u>>3,c=(u&7)<<3; pK[i]=*(const int4*)&gK[(size_t)r*512 + c]; }
  #pragma unroll
  for (int i=0;i<4;++i){ int u=tid+i*256; int r=u>>4,c=(u&15)<<3; pV[i]=*(const int4*)&gV[(size_t)r*2048 + c]; }
  if (tid<32) pD = *(const float4*)&gD[tid*4];
  for (int nc=0; nc<8; ++nc){
    // stage regs -> padded LDS
    #pragma unroll
    for (int i=0;i<4;++i){ int u=tid+i*256; int r=u>>3,c=(u&7)<<3; *(int4*)&sK[r*72+c]=pK[i]; }
    #pragma unroll
    for (int i=0;i<4;++i){ int u=tid+i*256; int r=u>>4,c=(u&15)<<3; *(int4*)&sV[r*136+c]=pV[i]; }
    if (tid<32) *(float4*)&sDg[tid*4] = pD;
    __syncthreads();
    // prefetch next chunk early: covered by feature MFMA + exp + PV
    if (nc<7){
      #pragma unroll
      for (int i=0;i<4;++i){ int u=tid+i*256; int r=u>>3,c=(u&7)<<3; pK[i]=*(const int4*)&gK[(size_t)((nc+1)*128+r)*512 + c]; }
      #pragma unroll
      for (int i=0;i<4;++i){ int u=tid+i*256; int r=u>>4,c=(u&15)<<3; pV[i]=*(const int4*)&gV[(size_t)r*2048 + (nc+1)*128 + c]; }
      if (tid<32) pD = *(const float4*)&gD[(nc+1)*128 + tid*4];
    }
    // feature MFMA: dd[128 n][64 m]
    f32x4 facc[2][4];
    #pragma unroll
    for (int rt=0;rt<2;++rt){
      int ar=(w*2+rt)*16+fr;
      #pragma unroll
      for (int mt=0;mt<4;++mt){
        f32x4 a={0.f,0.f,0.f,0.f};
        a=MFMA16(*(const bf16x8*)&sK[ar*72+kb],    *(const bf16x8*)&sP[(mt*16+fr)*72+kb],    a);
        a=MFMA16(*(const bf16x8*)&sK[ar*72+32+kb], *(const bf16x8*)&sP[(mt*16+fr)*72+32+kb], a);
        facc[rt][mt]=a;
        lm=fmaxf(lm, fmaxf(fmaxf(a[0],a[1]),fmaxf(a[2],a[3])));
      }
    }
    // exp -> sT[m][n] (diag pre-staged: no barrier needed between MFMA and exp)
    #pragma unroll
    for (int rt=0;rt<2;++rt){
      int nl=(w*2+rt)*16+rowg;
      #pragma unroll
      for (int mt=0;mt<4;++mt){
        int ml=mt*16+fr;
        s16x4 pk;
        #pragma unroll
        for (int j=0;j<4;++j) pk[j]=(short)f2bf(__expf(facc[rt][mt][j]-sDg[nl+j]));
        *(s16x4*)&sT[ml*136+nl]=pk;
      }
    }
    __syncthreads();
    // PV MFMA + S partial (vectorized LDS reads)
    int am=w*16+fr;
    #pragma unroll
    for (int ct=0;ct<4;++ct){
      #pragma unroll
      for (int ks=0;ks<4;++ks){
        accc[ct]=MFMA16(*(const bf16x8*)&sT[am*136+ks*32+kb],
                        *(const bf16x8*)&sV[(ct*16+fr)*136+ks*32+kb], accc[ct]);
      }
    }
    {
      int m=tid>>2, q=tid&3;
      #pragma unroll
      for (int n8=0;n8<4;++n8){
        bf16x8 v=*(const bf16x8*)&sT[m*136+q*32+n8*8];
        #pragma unroll
        for (int j=0;j<8;++j) sS += bf2f((u16)v[j]);
      }
    }
    __syncthreads();
  }
  // S partial store
  {
    int m=tid>>2, q=tid&3;
    float t=sS;
    t += __shfl_xor(t,1,64); t += __shfl_xor(t,2,64);
    if (q==0) kcsP[(size_t)(s*32+bh)*512 + m0 + m] = t;
  }
  // mk
  #pragma unroll
  for (int m2=1;m2<64;m2<<=1) lm=fmaxf(lm,__shfl_xor(lm,m2,64));
  if (lane==0) red[w]=lm;
  __syncthreads();
  if (tid==0) atomicMax(&kmaxEnc[bh], encf(fmaxf(fmaxf(red[0],red[1]),fmaxf(red[2],red[3]))));
  // ctx partial f32, transposed [d][m] via LDS bounce (reuse sT as float[64][68])
  float* sTf = (float*)sT;
  int mloc = w*16+rowg;
  #pragma unroll
  for (int ct=0;ct<4;++ct){
    #pragma unroll
    for (int j=0;j<4;++j) sTf[(ct*16+fr)*68 + mloc + j] = accc[ct][j];
  }
  __syncthreads();
  for (int u=tid; u<1024; u+=256){
    int r=u>>4, c=(u&15)*4;
    *(float4*)&ctxPT[((size_t)(s*32+bh)*64 + r)*512 + m0 + c] = *(const float4*)&sTf[r*68+c];
  }
}

// ---------------- combine split-n partials: ctxT bf16 + kcs ----------------
__global__ __launch_bounds__(256) void k_comb(const float* __restrict__ ctxPT, u16* __restrict__ ctxT,
                                              const float* __restrict__ kcsP, float* __restrict__ kcs){
  int bh=blockIdx.x, dblk=blockIdx.y;
  int tid=threadIdx.x;
  int d0=dblk*8;
  const float* p0 = ctxPT + ((size_t)bh*64 + d0)*512;
  const float* p1 = ctxPT + ((size_t)(32+bh)*64 + d0)*512;
  u16* o = ctxT + ((size_t)bh*64 + d0)*512;
  for (int u=tid; u<1024; u+=256){
    int r=u>>7, c=(u&127)*4;
    float4 a=*(const float4*)&p0[(size_t)r*512+c];
    float4 bq=*(const float4*)&p1[(size_t)r*512+c];
    u16 t[4]={f2bf(a.x+bq.x),f2bf(a.y+bq.y),f2bf(a.z+bq.z),f2bf(a.w+bq.w)};
    *(int2*)&o[(size_t)r*512+c] = *(const int2*)t;
  }
  if (dblk==0){
    for (int u=tid; u<512; u+=256)
      kcs[(size_t)bh*512+u] = kcsP[(size_t)bh*512+u] + kcsP[(size_t)(32+bh)*512+u];
  }
}

// ---------------- q features (exp-only) + PV + exact eps epilogue ----------------
// grid (8 h, 16 chunk, 4 b): x = h for XCD L2 locality on ctxT/kcs.
__global__ __launch_bounds__(256) void k_qpout2(const u16* __restrict__ qB, const u16* __restrict__ projS,
    const float* __restrict__ kcs, const u16* __restrict__ ctxT,
    const float* __restrict__ ctxsum, const float* __restrict__ kcssum,
    const float* __restrict__ vsum, const u32* __restrict__ kmaxEnc,
    u16* __restrict__ outc)
{
  int h=blockIdx.x, chunk=blockIdx.y, b=blockIdx.z;
  int bh=b*8+h;
  int t0 = b*2048 + chunk*128;
  __shared__ u16 sP[2][64*64];
  __shared__ u16 sCt[2][64*64];
  __shared__ u16 qpL[128*72];
  __shared__ float sK[512];
  __shared__ float diag[128];
  int tid=threadIdx.x, w=tid>>6, lane=tid&63;
  int fr=lane&15, kb=(lane>>4)*8, rowg=(lane>>4)*4;
  bf16x8 qf[2][2];
  #pragma unroll
  for (int rt=0;rt<2;++rt)
    #pragma unroll
    for (int kc=0;kc<2;++kc)
      qf[rt][kc] = *(const bf16x8*)&qB[(size_t)(t0 + w*32 + rt*16 + fr)*512 + h*64 + kc*32 + kb];
  #pragma unroll
  for (int rt=0;rt<2;++rt){
    float s=0.f;
    #pragma unroll
    for (int kc=0;kc<2;++kc)
      #pragma unroll
      for (int j=0;j<8;++j){ float f=bf2f((u16)qf[rt][kc][j]); s+=f*f; }
    s += __shfl_xor(s,16,64); s += __shfl_xor(s,32,64);
    if (lane<16) diag[w*32 + rt*16 + fr] = 0.0625f*s;
  }
  for (int u=tid; u<512; u+=256) sK[u] = kcs[(size_t)bh*512 + u];
  {
    const u16* gp = projS;
    const u16* gc = ctxT + (size_t)bh*64*512;
    int lr=lane>>3, lc=(lane&7)*8;
    #pragma unroll
    for (int i=0;i<2;++i){
      int idx = w*2+i;
      async_lds16(&sP[0][idx*512], gp + idx*512 + lane*8);
      async_lds16(&sCt[0][idx*512], gc + (size_t)(idx*8+lr)*512 + lc);
    }
  }
  f32x4 acc2[2][4]={};
  float mx[2][4], dp[2][4], rs[2][4];
  #pragma unroll
  for (int rt=0;rt<2;++rt)
    #pragma unroll
    for (int j=0;j<4;++j){ mx[rt][j]=-3.0e38f; dp[rt][j]=0.f; rs[rt][j]=0.f; }
  __syncthreads();
  for (int mc=0; mc<8; ++mc){
    int cur = mc&1;
    if (mc<7){
      int nxt = cur^1;
      const u16* gp = projS + (mc+1)*64*64;
      const u16* gc = ctxT + (size_t)bh*64*512 + (mc+1)*64;
      int lr=lane>>3, lc=(lane&7)*8;
      #pragma unroll
      for (int i=0;i<2;++i){
        int idx = w*2+i;
        async_lds16(&sP[nxt][idx*512], gp + idx*512 + lane*8);
        async_lds16(&sCt[nxt][idx*512], gc + (size_t)(idx*8+lr)*512 + lc);
      }
    }
    f32x4 facc[2][4];
    #pragma unroll
    for (int rt=0;rt<2;++rt){
      #pragma unroll
      for (int mt=0;mt<4;++mt){
        f32x4 a={0.f,0.f,0.f,0.f};
        #pragma unroll
        for (int kc=0;kc<2;++kc){
          bf16x8 bv = *(const bf16x8*)&sP[cur][(mt*16+fr)*64 + kc*32 + kb];
          a = MFMA16(qf[rt][kc], bv, a);
        }
        facc[rt][mt]=a;
      }
    }
    #pragma unroll
    for (int rt=0;rt<2;++rt){
      #pragma unroll
      for (int mt=0;mt<4;++mt){
        #pragma unroll
        for (int j=0;j<4;++j){
          int rl = w*32 + rt*16 + rowg + j;
          mx[rt][j] = fmaxf(mx[rt][j], facc[rt][mt][j]);
          float vq = __expf(facc[rt][mt][j] - diag[rl]);
          u16 us = f2bf(vq);
          qpL[rl*72 + mt*16 + fr] = us;
          float uf = bf2f(us);
          dp[rt][j] += uf*sK[mc*64 + mt*16 + fr];
          rs[rt][j] += uf;
        }
      }
    }
    __syncthreads();
    #pragma unroll
    for (int rt=0;rt<2;++rt){
      #pragma unroll
      for (int ct=0;ct<4;++ct){
        #pragma unroll
        for (int kc=0;kc<2;++kc){
          bf16x8 av = *(const bf16x8*)&qpL[(w*32+rt*16+fr)*72 + kc*32 + kb];
          bf16x8 bv = *(const bf16x8*)&sCt[cur][(ct*16+fr)*64 + kc*32 + kb];
          acc2[rt][ct] = MFMA16(av,bv,acc2[rt][ct]);
        }
      }
    }
    __syncthreads();
  }
  #pragma unroll
  for (int rt=0;rt<2;++rt){
    #pragma unroll
    for (int j=0;j<4;++j){
      #pragma unroll
      for (int s=1;s<16;s<<=1){
        dp[rt][j] += __shfl_xor(dp[rt][j],s,64);
        rs[rt][j] += __shfl_xor(rs[rt][j],s,64);
        mx[rt][j]  = fmaxf(mx[rt][j], __shfl_xor(mx[rt][j],s,64));
      }
    }
  }
  float mk  = decf(kmaxEnc[bh]);
  float emk = __expf(mk);
  float Ssum = kcssum[bh];
  const float eps=1e-4f;
  float emq[2][4];
  #pragma unroll
  for (int rt=0;rt<2;++rt)
    #pragma unroll
    for (int j=0;j<4;++j) emq[rt][j]=__expf(mx[rt][j]);
  #pragma unroll
  for (int rt=0;rt<2;++rt){
    #pragma unroll
    for (int ct=0;ct<4;++ct){
      int d = ct*16 + fr;
      float cs = ctxsum[bh*64 + d];
      float vs = vsum[bh*64 + d];
      #pragma unroll
      for (int j=0;j<4;++j){
        float eq = emq[rt][j];
        float numer = acc2[rt][ct][j] + eps*(emk*vs*rs[rt][j] + eq*cs + eps*eq*emk*512.0f*vs);
        float den   = dp[rt][j]       + eps*(emk*2048.0f*rs[rt][j] + eq*Ssum + eps*eq*emk*512.0f*2048.0f);
        int row = t0 + w*32 + rt*16 + rowg + j;
        outc[(size_t)row*512 + h*64 + d] = f2bf(numer/den);
      }
    }
  }
}

extern "C" void kernel_launch(void* const* d_in, const int* in_sizes, int n_in,
                              void* d_out, int out_size, void* d_ws, size_t ws_size,
                              hipStream_t stream)
{
  (void)in_sizes; (void)n_in; (void)out_size; (void)ws_size;
  const float* x    = (const float*)d_in[0];
  const float* Wq   = (const float*)d_in[1];
  const float* bq   = (const float*)d_in[2];
  const float* Wk   = (const float*)d_in[3];
  const float* bk   = (const float*)d_in[4];
  const float* Wv   = (const float*)d_in[5];
  const float* bv   = (const float*)d_in[6];
  const float* Wo   = (const float*)d_in[7];
  const float* bo   = (const float*)d_in[8];
  const float* proj = (const float*)d_in[9];

  char* w = (char*)d_ws;
  size_t off=0;
  auto alloc=[&](size_t bytes)->char*{ char* p=w+off; off=(off+bytes+255)&~(size_t)255; return p; };
  u16*  xb   = (u16*)alloc(8192ull*512*2);
  u16*  qB   = (u16*)alloc(8192ull*512*2);
  u16*  kBf  = (u16*)alloc(8192ull*512*2);
  u16*  vB   = (u16*)alloc(8192ull*512*2);
  u16*  vT   = (u16*)alloc(32ull*64*2048*2);
  u16*  WqT  = (u16*)alloc(512ull*512*2);
  u16*  WkT  = (u16*)alloc(512ull*512*2);
  u16*  WvT  = (u16*)alloc(512ull*512*2);
  u16*  WoT  = (u16*)alloc(512ull*512*2);
  u16*  projS= (u16*)alloc(512ull*64*2);
  u16*  ctxT = (u16*)alloc(32ull*64*512*2);
  float* ctxPT=(float*)alloc(2ull*32*64*512*4);
  float* kcs = (float*)alloc(32ull*512*4);
  float* kcsP= (float*)alloc(2ull*32*512*4);
  float* diagK=(float*)alloc(32ull*2048*4);
  u32*  kmx  = (u32*)alloc(256);
  float* ctxs= (float*)alloc(32ull*64*4);
  float* kcss= (float*)alloc(32ull*4);
  float* vsm = (float*)alloc(32ull*64*4);
  u16*  outc = kBf;  // kBf dead after k_kpctx3; reuse

  dim3 TB(256);
  k_init<<<dim3(256),TB,0,stream>>>(kmx,projS,proj,x,xb);
  k_trw<<<dim3(16,16,4),TB,0,stream>>>(Wq,Wk,Wv,Wo, WqT,WkT,WvT,WoT);
  k_gemm2<false><<<dim3(64,8,3),TB,0,stream>>>(xb, WqT,WkT,WvT, bq,bk,bv, qB,kBf,vB);
  k_trv<<<dim3(2,64,32),TB,0,stream>>>(vB, vT);
  k_vsum<<<dim3(32),TB,0,stream>>>(vB, vsm);
  k_kdiag<<<dim3(32,8),TB,0,stream>>>(kBf, diagK);
  k_kpctx3<<<dim3(8,16,4),TB,0,stream>>>(kBf, projS, vT, diagK, ctxPT, kcsP, kmx);
  k_comb<<<dim3(32,8),TB,0,stream>>>(ctxPT, ctxT, kcsP, kcs);
  k_sums<<<dim3(32),TB,0,stream>>>(ctxT, kcs, ctxs, kcss);
  k_qpout2<<<dim3(8,16,4),TB,0,stream>>>(qB, projS, kcs, ctxT, ctxs, kcss, vsm, kmx, outc);
  k_gemm2<true><<<dim3(64,8,1),TB,0,stream>>>(outc, WoT,WoT,WoT, bo,bo,bo,
                                              d_out,d_out,d_out);
}